// Round 1
// 853.861 us; speedup vs baseline: 1.1478x; 1.1478x over previous
//
#include <hip/hip_runtime.h>
#include <cstddef>
#include <cstdint>

// ---------------- problem constants ----------------
#define B_SZ    2
#define SEQ     2048
#define DMODEL  2048
#define DINNER  4096
#define DSTATE  128
#define NHEADS  64
#define HEADDIM 64
#define DXBC    4352          // DINNER + 2*DSTATE
#define NPROJ   8448          // DINNER + DXBC (z | xBC); dt handled separately in fp32
#define CHUNK   64
#define NCHUNK  32
#define TOKENS  (B_SZ*SEQ)    // 4096

typedef __attribute__((ext_vector_type(8))) short short8;   // 8 x bf16
typedef __attribute__((ext_vector_type(4))) float floatx4;

// ---- bf16 <-> f32 helpers ----
__device__ inline float us2f(unsigned short u) {
  union { uint32_t i; float f; } c; c.i = ((uint32_t)u) << 16; return c.f;
}
__device__ inline unsigned short f2us(float f) {
  union { float f; uint32_t i; } c; c.f = f;
  uint32_t r = (c.i + 0x7fffu + ((c.i >> 16) & 1u)) >> 16;
  return (unsigned short)r;
}
__device__ inline float plo(uint32_t v) {
  union { uint32_t i; float f; } c; c.i = v << 16; return c.f;
}
__device__ inline float phi(uint32_t v) {
  union { uint32_t i; float f; } c; c.i = v & 0xffff0000u; return c.f;
}

// ---------------- f32 -> bf16 cast (vectorized) ----------------
__global__ __launch_bounds__(256) void cast_f32_bf16(
    const float* __restrict__ src, unsigned short* __restrict__ dst, int n) {
  int i = (blockIdx.x * 256 + threadIdx.x) * 4;
  if (i < n) {
    float4 v = *(const float4*)(src + i);
    ushort4 o;
    o.x = f2us(v.x); o.y = f2us(v.y); o.z = f2us(v.z); o.w = f2us(v.w);
    *(ushort4*)(dst + i) = o;
  }
}

// ---------------- MFMA bf16 NT GEMM: C[M,N] = A[M,K] @ B[N,K]^T ----------------
template<int OUT_BF16>
__global__ __launch_bounds__(256) void gemm_bt_mfma(
    const unsigned short* __restrict__ A, const unsigned short* __restrict__ B,
    void* __restrict__ Cout, int M, int N, int K) {
  __shared__ unsigned short sA[128*32];
  __shared__ unsigned short sB[128*32];
  const int tid  = threadIdx.x;
  const int lane = tid & 63;
  const int wave = tid >> 6;
  const int bm = blockIdx.y * 128;
  const int bn = blockIdx.x * 128;
  const int wm = (wave >> 1) * 64;
  const int wn = (wave & 1) * 64;
  const int fr = lane & 15;
  const int fq = lane >> 4;

  floatx4 acc[4][4];
  #pragma unroll
  for (int i = 0; i < 4; ++i)
    #pragma unroll
    for (int j = 0; j < 4; ++j) acc[i][j] = (floatx4){0.f, 0.f, 0.f, 0.f};

  const int g0 = tid * 8;
  for (int k0 = 0; k0 < K; k0 += 32) {
    __syncthreads();
    #pragma unroll
    for (int r = 0; r < 2; ++r) {
      int g = r * 2048 + g0;
      int row = g >> 5, col = g & 31;
      const unsigned short* gp = A + (size_t)(bm + row) * K + k0 + col;
      __builtin_amdgcn_global_load_lds(
          (const __attribute__((address_space(1))) uint32_t*)gp,
          (__attribute__((address_space(3))) uint32_t*)(sA + g), 16, 0, 0);
    }
    #pragma unroll
    for (int r = 0; r < 2; ++r) {
      int g = r * 2048 + g0;
      int row = g >> 5, col = g & 31;
      const unsigned short* gp = B + (size_t)(bn + row) * K + k0 + col;
      __builtin_amdgcn_global_load_lds(
          (const __attribute__((address_space(1))) uint32_t*)gp,
          (__attribute__((address_space(3))) uint32_t*)(sB + g), 16, 0, 0);
    }
    __syncthreads();

    short8 af[4], bfr[4];
    #pragma unroll
    for (int i = 0; i < 4; ++i)
      af[i] = *(const short8*)(sA + (wm + i*16 + fr) * 32 + fq * 8);
    #pragma unroll
    for (int j = 0; j < 4; ++j)
      bfr[j] = *(const short8*)(sB + (wn + j*16 + fr) * 32 + fq * 8);
    #pragma unroll
    for (int i = 0; i < 4; ++i)
      #pragma unroll
      for (int j = 0; j < 4; ++j)
        acc[i][j] = __builtin_amdgcn_mfma_f32_16x16x32_bf16(af[i], bfr[j], acc[i][j], 0, 0, 0);
  }

  #pragma unroll
  for (int i = 0; i < 4; ++i) {
    #pragma unroll
    for (int j = 0; j < 4; ++j) {
      int col = bn + wn + j*16 + fr;
      #pragma unroll
      for (int r = 0; r < 4; ++r) {
        int row = bm + wm + i*16 + fq*4 + r;
        if (OUT_BF16)
          ((unsigned short*)Cout)[(size_t)row * N + col] = f2us(acc[i][j][r]);
        else
          ((float*)Cout)[(size_t)row * N + col] = acc[i][j][r];
      }
    }
  }
}

// ---------------- fp32 tiled NT GEMM (fallback path only) ----------------
__device__ inline void loadA4(const float* p, float* d) {
  float4 v = *(const float4*)p; d[0]=v.x; d[1]=v.y; d[2]=v.z; d[3]=v.w;
}
__device__ inline void loadA4(const unsigned short* p, float* d) {
  ushort4 v = *(const ushort4*)p;
  d[0]=us2f(v.x); d[1]=us2f(v.y); d[2]=us2f(v.z); d[3]=us2f(v.w);
}
__device__ inline void store8(float* C, size_t off, const float* v) {
  *(float4*)(C + off)     = make_float4(v[0], v[1], v[2], v[3]);
  *(float4*)(C + off + 4) = make_float4(v[4], v[5], v[6], v[7]);
}
__device__ inline void store8(unsigned short* C, size_t off, const float* v) {
  ushort4 a; a.x=f2us(v[0]); a.y=f2us(v[1]); a.z=f2us(v[2]); a.w=f2us(v[3]);
  ushort4 b; b.x=f2us(v[4]); b.y=f2us(v[5]); b.z=f2us(v[6]); b.w=f2us(v[7]);
  *(ushort4*)(C + off) = a; *(ushort4*)(C + off + 4) = b;
}

template<typename AT, typename OT>
__global__ __launch_bounds__(256) void gemm_nt(
    const AT* __restrict__ A, const float* __restrict__ Bw,
    OT* __restrict__ C, int M, int N, int K) {
  __shared__ float As[16][128+4];
  __shared__ float Bs[16][128+4];
  const int bm = blockIdx.y * 128;
  const int bn = blockIdx.x * 128;
  const int tid = threadIdx.x;
  const int tx = tid & 15, ty = tid >> 4;

  float acc[8][8];
  #pragma unroll
  for (int i = 0; i < 8; ++i)
    #pragma unroll
    for (int j = 0; j < 8; ++j) acc[i][j] = 0.f;

  for (int k0 = 0; k0 < K; k0 += 16) {
    #pragma unroll
    for (int r = 0; r < 2; ++r) {
      int i = tid + r * 256;
      int m  = i >> 2;
      int kv = (i & 3) << 2;
      float va[4];
      loadA4(A + (size_t)(bm + m) * K + k0 + kv, va);
      As[kv+0][m] = va[0]; As[kv+1][m] = va[1]; As[kv+2][m] = va[2]; As[kv+3][m] = va[3];
      float vb[4] = {0.f, 0.f, 0.f, 0.f};
      if (bn + m < N) loadA4(Bw + (size_t)(bn + m) * K + k0 + kv, vb);
      Bs[kv+0][m] = vb[0]; Bs[kv+1][m] = vb[1]; Bs[kv+2][m] = vb[2]; Bs[kv+3][m] = vb[3];
    }
    __syncthreads();
    #pragma unroll
    for (int kk = 0; kk < 16; ++kk) {
      float ra[8], rb[8];
      *(float4*)&ra[0] = *(const float4*)&As[kk][ty*8];
      *(float4*)&ra[4] = *(const float4*)&As[kk][ty*8+4];
      *(float4*)&rb[0] = *(const float4*)&Bs[kk][tx*8];
      *(float4*)&rb[4] = *(const float4*)&Bs[kk][tx*8+4];
      #pragma unroll
      for (int i = 0; i < 8; ++i)
        #pragma unroll
        for (int j = 0; j < 8; ++j) acc[i][j] += ra[i] * rb[j];
    }
    __syncthreads();
  }
  #pragma unroll
  for (int i = 0; i < 8; ++i) {
    int m  = bm + ty*8 + i;
    int n0 = bn + tx*8;
    if (n0 < N) store8(C, (size_t)m * N + n0, &acc[i][0]);
  }
}

// ---------------- dt GEMM (fp32, tiled): dtr[t][h] = x[t,:] . W[NPROJ+h,:] ----
// Replaces per-token dt_gemv (245us: 4096 blocks re-read 512KB W slice => 2GB L2
// traffic). BM=64 tokens x BN=64 heads (all) x BK=32, 64 blocks, 4x4 reg tile.
// W traffic 2GB -> 32MB; compute ~1.07 GFLOP fp32.
__global__ __launch_bounds__(256) void dt_gemm(
    const float* __restrict__ x, const float* __restrict__ W,
    float* __restrict__ dtr) {
  __shared__ float sX[32][64];   // [kk][token]
  __shared__ float sW[32][64];   // [kk][head]
  const int tid = threadIdx.x;
  const int t0 = blockIdx.x * 64;
  const int tx = tid & 15;       // heads tx*4 .. tx*4+3
  const int ty = tid >> 4;       // tokens ty*4 .. ty*4+3
  const float* Wdt = W + (size_t)NPROJ * DMODEL;

  float acc[4][4];
  #pragma unroll
  for (int i = 0; i < 4; ++i)
    #pragma unroll
    for (int j = 0; j < 4; ++j) acc[i][j] = 0.f;

  const int r  = tid >> 3;        // 0..31
  const int kq = (tid & 7) * 4;   // 0,4,..,28

  for (int k0 = 0; k0 < DMODEL; k0 += 32) {
    __syncthreads();
    // stage x tile: 64 tokens x 32 k (coalesced float4 along k, transposed store)
    #pragma unroll
    for (int rr = 0; rr < 2; ++rr) {
      int t = r + rr * 32;
      float4 v = *(const float4*)(x + (size_t)(t0 + t) * DMODEL + k0 + kq);
      sX[kq+0][t] = v.x; sX[kq+1][t] = v.y; sX[kq+2][t] = v.z; sX[kq+3][t] = v.w;
    }
    // stage W tile: 64 heads x 32 k
    #pragma unroll
    for (int rr = 0; rr < 2; ++rr) {
      int hh = r + rr * 32;
      float4 v = *(const float4*)(Wdt + (size_t)hh * DMODEL + k0 + kq);
      sW[kq+0][hh] = v.x; sW[kq+1][hh] = v.y; sW[kq+2][hh] = v.z; sW[kq+3][hh] = v.w;
    }
    __syncthreads();
    #pragma unroll
    for (int kk = 0; kk < 32; ++kk) {
      float4 ra = *(const float4*)&sX[kk][ty*4];
      float4 rb = *(const float4*)&sW[kk][tx*4];
      float a[4] = {ra.x, ra.y, ra.z, ra.w};
      float b[4] = {rb.x, rb.y, rb.z, rb.w};
      #pragma unroll
      for (int i = 0; i < 4; ++i)
        #pragma unroll
        for (int j = 0; j < 4; ++j)
          acc[i][j] += a[i] * b[j];
    }
  }
  #pragma unroll
  for (int i = 0; i < 4; ++i) {
    float4 o = make_float4(acc[i][0], acc[i][1], acc[i][2], acc[i][3]);
    *(float4*)(dtr + (size_t)(t0 + ty*4 + i) * NHEADS + tx*4) = o;
  }
}

// ================= split-scan path =================
__global__ __launch_bounds__(256) void bc_conv_g(
    const unsigned short* __restrict__ proj, const float* __restrict__ cw,
    const float* __restrict__ cb, unsigned short* __restrict__ bcact,
    float* __restrict__ gbuf) {
  const int c = blockIdx.x & 31;
  const int b = blockIdx.x >> 5;
  const int tid = threadIdx.x;
  const int t0 = b * SEQ + c * CHUNK;
  __shared__ unsigned short sB[64*130];
  __shared__ unsigned short sC[64*130];
  for (int i = tid; i < 64*256; i += 256) {
    int s = i >> 8, ch = i & 255;
    int cx = 4096 + ch;
    int lb = c * CHUNK + s;
    float acc = cb[cx];
    #pragma unroll
    for (int j = 0; j < 4; ++j) {
      int ll = lb - 3 + j;
      if (ll >= 0)
        acc += cw[cx*4 + j] * us2f(proj[(size_t)(b*SEQ + ll) * NPROJ + DINNER + cx]);
    }
    float v = acc / (1.f + expf(-acc));
    unsigned short uv = f2us(v);
    if (ch < 128) sB[s*130 + ch] = uv;
    else          sC[s*130 + (ch - 128)] = uv;
    bcact[(size_t)(t0 + s) * 256 + ch] = uv;
  }
  __syncthreads();
  const int l = tid >> 2, q = tid & 3;
  float g[16];
  #pragma unroll
  for (int j = 0; j < 16; ++j) g[j] = 0.f;
  const uint32_t* Cu = (const uint32_t*)&sC[l * 130];
  for (int u = 0; u < 64; ++u) {
    uint32_t cv = Cu[u];
    float c0 = plo(cv), c1 = phi(cv);
    #pragma unroll
    for (int j = 0; j < 16; ++j) {
      uint32_t bv = ((const uint32_t*)&sB[(q*16 + j) * 130])[u];
      g[j] += c0 * plo(bv) + c1 * phi(bv);
    }
  }
  float* gr = gbuf + ((size_t)(b*NCHUNK + c)) * 4096 + l*64 + q*16;
  #pragma unroll
  for (int j = 0; j < 16; ++j) gr[j] = g[j];
}

// ---- A2 (MFMA): per (b,c,h): dt/cumsum, conv X, Y_diag+D-skip, chunk state ----
__global__ __launch_bounds__(256, 4) void ssd_phase_a2_mfma(
    const unsigned short* __restrict__ proj, const unsigned short* __restrict__ bcact,
    const float* __restrict__ dtr, const float* __restrict__ cw,
    const float* __restrict__ cb, const float* __restrict__ A_log,
    const float* __restrict__ dt_bias, const float* __restrict__ gbuf,
    const float* __restrict__ Dv,
    unsigned short* __restrict__ cs, float* __restrict__ acs,
    unsigned short* __restrict__ yscan) {
  const int h = blockIdx.x & 63;
  const int c = (blockIdx.x >> 6) & 31;
  const int b = blockIdx.x >> 11;
  const int tid = threadIdx.x;
  const int t0 = b * SEQ + c * CHUNK;
  const int lane = tid & 63, wave = tid >> 6;
  const int fr = lane & 15, fq = lane >> 4;

  __shared__ __align__(16) unsigned short sBt[128*72];  // Bt'[n][s]
  __shared__ __align__(16) unsigned short sXh[64*72];   // Xh[p][s] (transposed xh)
  __shared__ __align__(16) unsigned short sW[64*72];    // W'[l][s]
  __shared__ float sdt[64], sAc[64], sdecay[64];

  const float Ah = -expf(A_log[h]);
  if (tid < 64) {
    float raw = dtr[(size_t)(t0 + tid) * NHEADS + h] + dt_bias[h];
    float dt = (raw > 20.f) ? raw : log1pf(expf(raw));
    sdt[tid] = dt;
    float v = dt * Ah;
    #pragma unroll
    for (int off = 1; off < 64; off <<= 1) {
      float o = __shfl_up(v, off, 64);
      if (tid >= off) v += o;
    }
    sAc[tid] = v;
    float alast = __shfl(v, 63, 64);
    sdecay[tid] = expf(alast - v);
    acs[((size_t)((b*NHEADS + h)*NCHUNK + c))*64 + tid] = v;
  }
  __syncthreads();
  for (int i = tid; i < 64*128; i += 256) {
    int s = i >> 7, n = i & 127;
    float v = us2f(bcact[(size_t)(t0 + s) * 256 + n]) * sdt[s] * sdecay[s];
    sBt[n*72 + s] = f2us(v);
  }
  for (int i = tid; i < 64*64; i += 256) {
    int s = i >> 6, p = i & 63;
    int cx = h * HEADDIM + p;
    int lb = c * CHUNK + s;
    float acc = cb[cx];
    #pragma unroll
    for (int j = 0; j < 4; ++j) {
      int ll = lb - 3 + j;
      if (ll >= 0)
        acc += cw[cx*4 + j] * us2f(proj[(size_t)(b*SEQ + ll) * NPROJ + DINNER + cx]);
    }
    float xh = acc / (1.f + expf(-acc));
    sXh[p*72 + s] = f2us(xh);
  }
  {
    const float* gr = gbuf + ((size_t)(b*NCHUNK + c)) * 4096;
    for (int i = tid; i < 4096; i += 256) {
      int l = i >> 6, s = i & 63;
      float w = (s <= l) ? gr[i] * expf(sAc[l] - sAc[s]) * sdt[s] : 0.f;
      sW[l*72 + s] = f2us(w);
    }
  }
  __syncthreads();

  floatx4 accy[4];
  #pragma unroll
  for (int j = 0; j < 4; ++j) accy[j] = (floatx4){0.f, 0.f, 0.f, 0.f};
  #pragma unroll
  for (int k0 = 0; k0 < 64; k0 += 32) {
    short8 af = *(const short8*)(sW + (wave*16 + fr)*72 + k0 + fq*8);
    #pragma unroll
    for (int j = 0; j < 4; ++j) {
      short8 bf = *(const short8*)(sXh + (j*16 + fr)*72 + k0 + fq*8);
      accy[j] = __builtin_amdgcn_mfma_f32_16x16x32_bf16(af, bf, accy[j], 0, 0, 0);
    }
  }
  const float Dh = Dv[h];
  #pragma unroll
  for (int j = 0; j < 4; ++j) {
    int p = j*16 + fr;
    #pragma unroll
    for (int r = 0; r < 4; ++r) {
      int l = wave*16 + fq*4 + r;
      float yd = accy[j][r] + us2f(sXh[p*72 + l]) * Dh;
      yscan[(size_t)(t0 + l) * DINNER + h*HEADDIM + p] = f2us(yd);
    }
  }
  floatx4 accs[8];
  #pragma unroll
  for (int j = 0; j < 8; ++j) accs[j] = (floatx4){0.f, 0.f, 0.f, 0.f};
  #pragma unroll
  for (int k0 = 0; k0 < 64; k0 += 32) {
    short8 af = *(const short8*)(sXh + (wave*16 + fr)*72 + k0 + fq*8);
    #pragma unroll
    for (int j = 0; j < 8; ++j) {
      short8 bf = *(const short8*)(sBt + (j*16 + fr)*72 + k0 + fq*8);
      accs[j] = __builtin_amdgcn_mfma_f32_16x16x32_bf16(af, bf, accs[j], 0, 0, 0);
    }
  }
  const size_t csb = ((size_t)((b*NHEADS + h)*NCHUNK + c)) * (HEADDIM*DSTATE);
  #pragma unroll
  for (int j = 0; j < 8; ++j) {
    int n = j*16 + fr;
    #pragma unroll
    for (int r = 0; r < 4; ++r) {
      int p = wave*16 + fq*4 + r;
      cs[csb + p*128 + n] = f2us(accs[j][r]);
    }
  }
}

// ---- B: inter-chunk running-state scan ----
__global__ __launch_bounds__(256) void ssd_scan_states(
    unsigned short* __restrict__ cs, const float* __restrict__ acs) {
  int idx = blockIdx.x * 256 + threadIdx.x;
  int e  = idx & 8191;
  int bh = idx >> 13;
  float S = 0.f;
  for (int c = 0; c < NCHUNK; ++c) {
    float al = acs[((size_t)bh*NCHUNK + c)*64 + 63];
    size_t o = ((size_t)bh*NCHUNK + c)*(HEADDIM*DSTATE) + e;
    S = S * expf(al) + us2f(cs[o]);
    cs[o] = f2us(S);
  }
}

// ---- C (MFMA): Y += (C @ S^T) * exp(Ac[l]) ----
__global__ __launch_bounds__(256, 4) void ssd_phase_c_mfma(
    const unsigned short* __restrict__ bcact, const unsigned short* __restrict__ cs,
    const float* __restrict__ acs, unsigned short* __restrict__ yscan) {
  const int h = blockIdx.x & 63;
  const int c = (blockIdx.x >> 6) & 31;
  const int b = blockIdx.x >> 11;
  const int tid = threadIdx.x;
  const int t0 = b * SEQ + c * CHUNK;
  const int lane = tid & 63, wave = tid >> 6;
  const int fr = lane & 15, fq = lane >> 4;

  __shared__ __align__(16) unsigned short sC[64*136];  // C[l][n]
  __shared__ __align__(16) unsigned short sS[64*136];  // S[p][n]
  __shared__ float seAc[64];

  const size_t csb = ((size_t)((b*NHEADS + h)*NCHUNK + c)) * (HEADDIM*DSTATE);
  for (int i = tid; i < 8192; i += 256) {
    int p = i >> 7, n = i & 127;
    sS[p*136 + n] = cs[csb + i];
  }
  for (int i = tid; i < 8192; i += 256) {
    int l = i >> 7, n = i & 127;
    sC[l*136 + n] = bcact[(size_t)(t0 + l) * 256 + 128 + n];
  }
  if (tid < 64) seAc[tid] = expf(acs[((size_t)((b*NHEADS + h)*NCHUNK + c))*64 + tid]);
  __syncthreads();

  floatx4 acc[4];
  #pragma unroll
  for (int j = 0; j < 4; ++j) acc[j] = (floatx4){0.f, 0.f, 0.f, 0.f};
  #pragma unroll
  for (int k0 = 0; k0 < 128; k0 += 32) {
    short8 af = *(const short8*)(sC + (wave*16 + fr)*136 + k0 + fq*8);
    #pragma unroll
    for (int j = 0; j < 4; ++j) {
      short8 bf = *(const short8*)(sS + (j*16 + fr)*136 + k0 + fq*8);
      acc[j] = __builtin_amdgcn_mfma_f32_16x16x32_bf16(af, bf, acc[j], 0, 0, 0);
    }
  }
  #pragma unroll
  for (int j = 0; j < 4; ++j) {
    int p = j*16 + fr;
    #pragma unroll
    for (int r = 0; r < 4; ++r) {
      int l = wave*16 + fq*4 + r;
      size_t yi = (size_t)(t0 + l) * DINNER + h*HEADDIM + p;
      yscan[yi] = f2us(us2f(yscan[yi]) + acc[j][r] * seAc[l]);
    }
  }
}

__global__ __launch_bounds__(256) void gate_rmsnorm2(
    const unsigned short* __restrict__ proj, const float* __restrict__ norm_w,
    unsigned short* __restrict__ yscan) {
  const int t = blockIdx.x;
  const int tid = threadIdx.x;
  __shared__ float ybuf[DINNER];
  __shared__ float wpart[4];
  __shared__ float sinv;
  float ss = 0.f;
  for (int i = tid; i < DINNER; i += 256) {
    float zv = us2f(proj[(size_t)t * NPROJ + i]);
    float yv = us2f(yscan[(size_t)t * DINNER + i]) * (zv / (1.f + expf(-zv)));
    ybuf[i] = yv;
    ss += yv * yv;
  }
  #pragma unroll
  for (int off = 32; off > 0; off >>= 1) ss += __shfl_down(ss, off, 64);
  if ((tid & 63) == 0) wpart[tid >> 6] = ss;
  __syncthreads();
  if (tid == 0) {
    float tot = wpart[0] + wpart[1] + wpart[2] + wpart[3];
    sinv = 1.f / sqrtf(tot / (float)DINNER + 1e-5f);
  }
  __syncthreads();
  float inv = sinv;
  for (int i = tid; i < DINNER; i += 256)
    yscan[(size_t)t * DINNER + i] = f2us(ybuf[i] * inv * norm_w[i]);
}

// ================= FALLBACK path =================
__global__ __launch_bounds__(512) void ssd_fused(
    const unsigned short* __restrict__ proj, const float* __restrict__ dtr,
    const float* __restrict__ cw, const float* __restrict__ cb,
    const float* __restrict__ A_log, const float* __restrict__ dt_bias,
    unsigned short* __restrict__ yscan) {
  const int h = blockIdx.x & 63;
  const int b = blockIdx.x >> 6;
  const int tid = threadIdx.x;

  __shared__ unsigned short sB[64*130];
  __shared__ unsigned short sC[64*130];
  __shared__ unsigned short sX[64*66];
  __shared__ float sW[64*65];
  __shared__ float sdt[64], sAc[64], sdecay[64], seAc[64];

  const float Ah = -expf(A_log[h]);
  const float dbias = dt_bias[h];

  float S[16];
  #pragma unroll
  for (int j = 0; j < 16; ++j) S[j] = 0.f;

  const int lG  = tid >> 3;
  const int oc  = tid & 7;

  for (int c = 0; c < NCHUNK; ++c) {
    const int t0 = b * SEQ + c * CHUNK;
    __syncthreads();
    if (tid < 64) {
      float raw = dtr[(size_t)(t0 + tid) * NHEADS + h] + dbias;
      sdt[tid] = (raw > 20.f) ? raw : log1pf(expf(raw));
    }
    for (int i = tid; i < 64*256; i += 512) {
      int s = i >> 8, ch = i & 255;
      int cx = 4096 + ch;
      int lb = c * CHUNK + s;
      float acc = cb[cx];
      #pragma unroll
      for (int j = 0; j < 4; ++j) {
        int ll = lb - 3 + j;
        if (ll >= 0)
          acc += cw[cx*4 + j] * us2f(proj[(size_t)(b*SEQ + ll) * NPROJ + DINNER + cx]);
      }
      float v = acc / (1.f + expf(-acc));
      if (ch < 128) sB[s*130 + ch] = f2us(v);
      else          sC[s*130 + (ch - 128)] = f2us(v);
    }
    __syncthreads();
    if (tid == 0) {
      float run = 0.f;
      for (int s = 0; s < CHUNK; ++s) { run += sdt[s] * Ah; sAc[s] = run; }
    }
    __syncthreads();
    if (tid < 64) {
      float last = sAc[63];
      sdecay[tid] = expf(last - sAc[tid]);
      seAc[tid]   = expf(sAc[tid]);
    }
    for (int i = tid; i < 64*64; i += 512) {
      int s = i >> 6, p = i & 63;
      int cx = h * HEADDIM + p;
      int lb = c * CHUNK + s;
      float acc = cb[cx];
      #pragma unroll
      for (int j = 0; j < 4; ++j) {
        int ll = lb - 3 + j;
        if (ll >= 0)
          acc += cw[cx*4 + j] * us2f(proj[(size_t)(b*SEQ + ll) * NPROJ + DINNER + cx]);
      }
      float v = acc / (1.f + expf(-acc));
      sX[s*66 + p] = f2us(v * sdt[s]);
    }
    __syncthreads();

    float g[8];
    #pragma unroll
    for (int j = 0; j < 8; ++j) g[j] = 0.f;
    {
      const uint32_t* Cu = (const uint32_t*)&sC[lG * 130];
      for (int u = 0; u < 64; ++u) {
        uint32_t cv = Cu[u];
        float c0 = plo(cv), c1 = phi(cv);
        #pragma unroll
        for (int j = 0; j < 8; ++j) {
          uint32_t bv = ((const uint32_t*)&sB[(oc*8 + j) * 130])[u];
          g[j] += c0 * plo(bv) + c1 * phi(bv);
        }
      }
    }
    {
      float acl = sAc[lG];
      #pragma unroll
      for (int j = 0; j < 8; ++j) {
        int s = oc*8 + j;
        sW[lG*65 + s] = (s <= lG) ? g[j] * expf(acl - sAc[s]) : 0.f;
      }
    }
    {
      float elast = expf(sAc[63]);
      #pragma unroll
      for (int j = 0; j < 16; ++j) S[j] *= elast;
      for (int s = 0; s < CHUNK; ++s) {
        float w = sdecay[s] * us2f(sX[s*66 + lG]);
        const uint32_t* Bu = (const uint32_t*)&sB[s*130 + oc*16];
        #pragma unroll
        for (int ju = 0; ju < 8; ++ju) {
          uint32_t bv = Bu[ju];
          S[2*ju]   += plo(bv) * w;
          S[2*ju+1] += phi(bv) * w;
        }
      }
    }
    __syncthreads();
    #pragma unroll
    for (int j = 0; j < 16; ++j) sB[lG*130 + oc*16 + j] = f2us(S[j]);
    __syncthreads();
    for (int o = tid; o < CHUNK*HEADDIM; o += 512) {
      int l = o >> 6, p = o & 63;
      float yd = 0.f;
      for (int s = 0; s <= l; ++s)
        yd += sW[l*65 + s] * us2f(sX[s*66 + p]);
      float yo = 0.f;
      const uint32_t* Cu = (const uint32_t*)&sC[l * 130];
      const uint32_t* Su = (const uint32_t*)&sB[p * 130];
      for (int u = 0; u < 64; ++u) {
        uint32_t cv = Cu[u], sv = Su[u];
        yo += plo(cv) * plo(sv) + phi(cv) * phi(sv);
      }
      float y = yd + yo * seAc[l];
      yscan[(size_t)(t0 + l) * DINNER + h * HEADDIM + p] = f2us(y);
    }
  }
}

__global__ __launch_bounds__(256) void gate_rmsnorm_dskip(
    const unsigned short* __restrict__ proj, const float* __restrict__ cw,
    const float* __restrict__ cb, const float* __restrict__ Dv,
    const float* __restrict__ norm_w, unsigned short* __restrict__ yscan) {
  const int t = blockIdx.x;
  const int tid = threadIdx.x;
  const int b = t >> 11, lb = t & 2047;
  __shared__ float ybuf[DINNER];
  __shared__ float wpart[4];
  __shared__ float sinv;
  float ss = 0.f;
  for (int i = tid; i < DINNER; i += 256) {
    float zv = us2f(proj[(size_t)t * NPROJ + i]);
    float acc = cb[i];
    #pragma unroll
    for (int j = 0; j < 4; ++j) {
      int ll = lb - 3 + j;
      if (ll >= 0)
        acc += cw[i*4 + j] * us2f(proj[(size_t)(b*SEQ + ll) * NPROJ + DINNER + i]);
    }
    float xh = acc / (1.f + expf(-acc));
    float yv = us2f(yscan[(size_t)t * DINNER + i]) + xh * Dv[i >> 6];
    yv = yv * (zv / (1.f + expf(-zv)));
    ybuf[i] = yv;
    ss += yv * yv;
  }
  #pragma unroll
  for (int off = 32; off > 0; off >>= 1) ss += __shfl_down(ss, off, 64);
  if ((tid & 63) == 0) wpart[tid >> 6] = ss;
  __syncthreads();
  if (tid == 0) {
    float tot = wpart[0] + wpart[1] + wpart[2] + wpart[3];
    sinv = 1.f / sqrtf(tot / (float)DINNER + 1e-5f);
  }
  __syncthreads();
  float inv = sinv;
  for (int i = tid; i < DINNER; i += 256)
    yscan[(size_t)t * DINNER + i] = f2us(ybuf[i] * inv * norm_w[i]);
}

// ---------------- launch ----------------
extern "C" void kernel_launch(void* const* d_in, const int* in_sizes, int n_in,
                              void* d_out, int out_size, void* d_ws, size_t ws_size,
                              hipStream_t stream) {
  const float* x          = (const float*)d_in[0];
  const float* in_proj_w  = (const float*)d_in[1];
  const float* conv_w     = (const float*)d_in[2];
  const float* conv_b     = (const float*)d_in[3];
  const float* A_log      = (const float*)d_in[4];
  const float* Dv         = (const float*)d_in[5];
  const float* dt_bias    = (const float*)d_in[6];
  const float* norm_w     = (const float*)d_in[7];
  const float* out_proj_w = (const float*)d_in[8];
  float* out = (float*)d_out;

  unsigned short* proj  = (unsigned short*)d_ws;
  float*          dtr   = (float*)(proj + (size_t)TOKENS * NPROJ);
  unsigned short* yscan = (unsigned short*)(dtr + (size_t)TOKENS * NHEADS);
  unsigned short* cs    = yscan + (size_t)TOKENS * DINNER;
  float*          acs   = (float*)(cs + (size_t)B_SZ*NHEADS*NCHUNK*HEADDIM*DSTATE);
  unsigned short* bcact = (unsigned short*)(acs + (size_t)B_SZ*NHEADS*NCHUNK*64);
  float*          gbuf  = (float*)(bcact + (size_t)TOKENS*256);
  const size_t NEEDED = (size_t)((char*)(gbuf + (size_t)B_SZ*NCHUNK*4096) - (char*)d_ws);

  unsigned short* xb  = cs;                                  // TOKENS*DMODEL
  unsigned short* wib = xb + (size_t)TOKENS * DMODEL;        // NPROJ*DMODEL
  unsigned short* wob = proj;                                // DMODEL*DINNER

  if (ws_size >= NEEDED) {
    cast_f32_bf16<<<(TOKENS*DMODEL)/1024, 256, 0, stream>>>(x, xb, TOKENS*DMODEL);
    cast_f32_bf16<<<((size_t)NPROJ*DMODEL)/1024, 256, 0, stream>>>(in_proj_w, wib, NPROJ*DMODEL);
    {
      dim3 grid(NPROJ/128, TOKENS/128);
      gemm_bt_mfma<1><<<grid, 256, 0, stream>>>(xb, wib, proj, TOKENS, NPROJ, DMODEL);
    }
    dt_gemm<<<TOKENS/64, 256, 0, stream>>>(x, in_proj_w, dtr);
    bc_conv_g<<<B_SZ*NCHUNK, 256, 0, stream>>>(proj, conv_w, conv_b, bcact, gbuf);
    ssd_phase_a2_mfma<<<B_SZ*NCHUNK*NHEADS, 256, 0, stream>>>(
        proj, bcact, dtr, conv_w, conv_b, A_log, dt_bias, gbuf, Dv, cs, acs, yscan);
    ssd_scan_states<<<(B_SZ*NHEADS*HEADDIM*DSTATE)/256, 256, 0, stream>>>(cs, acs);
    ssd_phase_c_mfma<<<B_SZ*NCHUNK*NHEADS, 256, 0, stream>>>(bcact, cs, acs, yscan);
    gate_rmsnorm2<<<TOKENS, 256, 0, stream>>>(proj, norm_w, yscan);
    cast_f32_bf16<<<((size_t)DMODEL*DINNER)/1024, 256, 0, stream>>>(out_proj_w, wob, DMODEL*DINNER);
    {
      dim3 grid(DMODEL/128, TOKENS/128);
      gemm_bt_mfma<0><<<grid, 256, 0, stream>>>(yscan, wob, out, TOKENS, DMODEL, DINNER);
    }
  } else {
    {
      dim3 grid(NPROJ/128, TOKENS/128);
      gemm_nt<float, unsigned short><<<grid, 256, 0, stream>>>(
          x, in_proj_w, proj, TOKENS, NPROJ, DMODEL);
    }
    dt_gemm<<<TOKENS/64, 256, 0, stream>>>(x, in_proj_w, dtr);
    ssd_fused<<<B_SZ*NHEADS, 512, 0, stream>>>(proj, dtr, conv_w, conv_b,
                                               A_log, dt_bias, yscan);
    gate_rmsnorm_dskip<<<TOKENS, 256, 0, stream>>>(proj, conv_w, conv_b, Dv, norm_w, yscan);
    {
      dim3 grid(DMODEL/128, TOKENS/128);
      gemm_nt<unsigned short, float><<<grid, 256, 0, stream>>>(
          yscan, out_proj_w, out, TOKENS, DMODEL, DINNER);
    }
  }
}

// Round 2
// 849.225 us; speedup vs baseline: 1.1541x; 1.0055x over previous
//
#include <hip/hip_runtime.h>
#include <cstddef>
#include <cstdint>

// ---------------- problem constants ----------------
#define B_SZ    2
#define SEQ     2048
#define DMODEL  2048
#define DINNER  4096
#define DSTATE  128
#define NHEADS  64
#define HEADDIM 64
#define DXBC    4352          // DINNER + 2*DSTATE
#define NPROJ   8448          // DINNER + DXBC (z | xBC); dt handled separately in fp32
#define CHUNK   64
#define NCHUNK  32
#define TOKENS  (B_SZ*SEQ)    // 4096

typedef __attribute__((ext_vector_type(8))) short short8;   // 8 x bf16
typedef __attribute__((ext_vector_type(4))) float floatx4;

// ---- bf16 <-> f32 helpers ----
__device__ inline float us2f(unsigned short u) {
  union { uint32_t i; float f; } c; c.i = ((uint32_t)u) << 16; return c.f;
}
__device__ inline unsigned short f2us(float f) {
  union { float f; uint32_t i; } c; c.f = f;
  uint32_t r = (c.i + 0x7fffu + ((c.i >> 16) & 1u)) >> 16;
  return (unsigned short)r;
}
__device__ inline float plo(uint32_t v) {
  union { uint32_t i; float f; } c; c.i = v << 16; return c.f;
}
__device__ inline float phi(uint32_t v) {
  union { uint32_t i; float f; } c; c.i = v & 0xffff0000u; return c.f;
}

// ---------------- f32 -> bf16 cast (vectorized) ----------------
__global__ __launch_bounds__(256) void cast_f32_bf16(
    const float* __restrict__ src, unsigned short* __restrict__ dst, int n) {
  int i = (blockIdx.x * 256 + threadIdx.x) * 4;
  if (i < n) {
    float4 v = *(const float4*)(src + i);
    ushort4 o;
    o.x = f2us(v.x); o.y = f2us(v.y); o.z = f2us(v.z); o.w = f2us(v.w);
    *(ushort4*)(dst + i) = o;
  }
}

// ============ 256x256 8-phase MFMA bf16 NT GEMM (T2+T3+T4+T5 template) =======
// C[M,N] = A[M,K] @ B[N,K]^T.  BK=64, 8 waves (2Mx4N), per-wave out 128x64.
// LDS 128KiB: 2 dbuf x (A[256][64] + B[256][64]) bf16.
// XOR-swizzle byte^=((row&7)<<4) applied BOTH sides: pre-swizzled global src
// for global_load_lds (linear LDS dest) + swizzled ds_read col.
// 4 phases per K-tile: {stage-issue | ds_read subtile, s_barrier, setprio(1),
// 16 MFMA, setprio(0), [vmcnt(0) at p3], s_barrier}. Raw barriers so loads
// stay in flight across phases; single vmcnt per K-tile.
template<int OUT_BF16>
__global__ __launch_bounds__(512, 1) void gemm_bt_256(
    const unsigned short* __restrict__ A, const unsigned short* __restrict__ B,
    void* __restrict__ Cout, int M, int N, int K) {
  __shared__ __align__(16) unsigned short sT[2][32768];  // [dbuf][A 16384 | B 16384]
  const int tid  = threadIdx.x;
  const int lane = tid & 63;
  const int wave = tid >> 6;        // 0..7
  const int wr   = wave >> 2;       // 0..1  (M dir)
  const int wc   = wave & 3;        // 0..3  (N dir)
  const int fr   = lane & 15;
  const int fq   = lane >> 4;
  const int bm   = blockIdx.y * 256;
  const int bn   = blockIdx.x * 256;

  floatx4 acc[8][4];
  #pragma unroll
  for (int i = 0; i < 8; ++i)
    #pragma unroll
    for (int j = 0; j < 4; ++j) acc[i][j] = (floatx4){0.f, 0.f, 0.f, 0.f};

  // staging geometry: chunk = 64 rows x 64 shorts (8KiB) = 1 x 16B load/thread.
  // chunks 0..3 = A quarters, 4..7 = B quarters.
  const int srow = tid >> 3;                       // row within quarter (0..63)
  const int scol = 8 * ((tid & 7) ^ (srow & 7));   // LOGICAL col (shorts), pre-swizzled
  const int xorm = (fr & 7) * 8;                   // read-side swizzle (shorts)

  auto stage = [&](int c, int k0base, unsigned short* dst) {
    const int part = c >> 2, q = c & 3;
    const int row  = q * 64 + srow;
    const unsigned short* g =
        (part ? B + (size_t)(bn + row) * K : A + (size_t)(bm + row) * K) + k0base + scol;
    unsigned short* l = dst + part * 16384 + q * 4096 + tid * 8;
    __builtin_amdgcn_global_load_lds(
        (const __attribute__((address_space(1))) uint32_t*)g,
        (__attribute__((address_space(3))) uint32_t*)l, 16, 0, 0);
  };

  // prologue: stage K-tile 0 into buf0
  #pragma unroll
  for (int c = 0; c < 8; ++c) stage(c, 0, &sT[0][0]);
  asm volatile("s_waitcnt vmcnt(0)" ::: "memory");
  asm volatile("s_barrier" ::: "memory");

  const int NT = K >> 6;
  for (int kt = 0; kt < NT; ++kt) {
    const int cur = kt & 1;
    const unsigned short* bufc = &sT[cur][0];
    unsigned short* bufn = &sT[cur ^ 1][0];
    const int k1 = (kt + 1) << 6;
    const bool pre = (kt + 1 < NT);

    short8 bf[2][4];   // B frags held across all 4 phases of this K-tile
    #pragma unroll
    for (int p = 0; p < 4; ++p) {
      // stage next K-tile, front-loaded (4 chunks in p0, 4 in p1)
      if (p < 2 && pre) {
        #pragma unroll
        for (int r = 0; r < 4; ++r) stage(p * 4 + r, k1, bufn);
      }
      // ds reads: B once (phase 0, 8 reads), A subtile每 phase (4 reads)
      if (p == 0) {
        #pragma unroll
        for (int ks = 0; ks < 2; ++ks)
          #pragma unroll
          for (int j = 0; j < 4; ++j) {
            int row = wc * 64 + j * 16 + fr;
            bf[ks][j] = *(const short8*)(bufc + 16384 + row * 64 +
                                         ((ks * 32 + fq * 8) ^ xorm));
          }
      }
      short8 af[2][2];
      #pragma unroll
      for (int ks = 0; ks < 2; ++ks)
        #pragma unroll
        for (int i = 0; i < 2; ++i) {
          int row = wr * 128 + (p * 2 + i) * 16 + fr;
          af[ks][i] = *(const short8*)(bufc + row * 64 +
                                       ((ks * 32 + fq * 8) ^ xorm));
        }
      asm volatile("s_barrier" ::: "memory");
      __builtin_amdgcn_s_setprio(1);
      #pragma unroll
      for (int ks = 0; ks < 2; ++ks)
        #pragma unroll
        for (int i = 0; i < 2; ++i)
          #pragma unroll
          for (int j = 0; j < 4; ++j)
            acc[p * 2 + i][j] = __builtin_amdgcn_mfma_f32_16x16x32_bf16(
                af[ks][i], bf[ks][j], acc[p * 2 + i][j], 0, 0, 0);
      __builtin_amdgcn_s_setprio(0);
      if (p == 3) asm volatile("s_waitcnt vmcnt(0)" ::: "memory");
      asm volatile("s_barrier" ::: "memory");
    }
  }

  // epilogue
  #pragma unroll
  for (int i = 0; i < 8; ++i) {
    #pragma unroll
    for (int j = 0; j < 4; ++j) {
      int col = bn + wc * 64 + j * 16 + fr;
      #pragma unroll
      for (int r = 0; r < 4; ++r) {
        int row = bm + wr * 128 + i * 16 + fq * 4 + r;
        if (OUT_BF16)
          ((unsigned short*)Cout)[(size_t)row * N + col] = f2us(acc[i][j][r]);
        else
          ((float*)Cout)[(size_t)row * N + col] = acc[i][j][r];
      }
    }
  }
}

// ---------------- 128x128 MFMA bf16 NT GEMM (kept for out-proj) --------------
template<int OUT_BF16>
__global__ __launch_bounds__(256) void gemm_bt_mfma(
    const unsigned short* __restrict__ A, const unsigned short* __restrict__ B,
    void* __restrict__ Cout, int M, int N, int K) {
  __shared__ unsigned short sA[128*32];
  __shared__ unsigned short sB[128*32];
  const int tid  = threadIdx.x;
  const int lane = tid & 63;
  const int wave = tid >> 6;
  const int bm = blockIdx.y * 128;
  const int bn = blockIdx.x * 128;
  const int wm = (wave >> 1) * 64;
  const int wn = (wave & 1) * 64;
  const int fr = lane & 15;
  const int fq = lane >> 4;

  floatx4 acc[4][4];
  #pragma unroll
  for (int i = 0; i < 4; ++i)
    #pragma unroll
    for (int j = 0; j < 4; ++j) acc[i][j] = (floatx4){0.f, 0.f, 0.f, 0.f};

  const int g0 = tid * 8;
  for (int k0 = 0; k0 < K; k0 += 32) {
    __syncthreads();
    #pragma unroll
    for (int r = 0; r < 2; ++r) {
      int g = r * 2048 + g0;
      int row = g >> 5, col = g & 31;
      const unsigned short* gp = A + (size_t)(bm + row) * K + k0 + col;
      __builtin_amdgcn_global_load_lds(
          (const __attribute__((address_space(1))) uint32_t*)gp,
          (__attribute__((address_space(3))) uint32_t*)(sA + g), 16, 0, 0);
    }
    #pragma unroll
    for (int r = 0; r < 2; ++r) {
      int g = r * 2048 + g0;
      int row = g >> 5, col = g & 31;
      const unsigned short* gp = B + (size_t)(bn + row) * K + k0 + col;
      __builtin_amdgcn_global_load_lds(
          (const __attribute__((address_space(1))) uint32_t*)gp,
          (__attribute__((address_space(3))) uint32_t*)(sB + g), 16, 0, 0);
    }
    __syncthreads();

    short8 af[4], bfr[4];
    #pragma unroll
    for (int i = 0; i < 4; ++i)
      af[i] = *(const short8*)(sA + (wm + i*16 + fr) * 32 + fq * 8);
    #pragma unroll
    for (int j = 0; j < 4; ++j)
      bfr[j] = *(const short8*)(sB + (wn + j*16 + fr) * 32 + fq * 8);
    #pragma unroll
    for (int i = 0; i < 4; ++i)
      #pragma unroll
      for (int j = 0; j < 4; ++j)
        acc[i][j] = __builtin_amdgcn_mfma_f32_16x16x32_bf16(af[i], bfr[j], acc[i][j], 0, 0, 0);
  }

  #pragma unroll
  for (int i = 0; i < 4; ++i) {
    #pragma unroll
    for (int j = 0; j < 4; ++j) {
      int col = bn + wn + j*16 + fr;
      #pragma unroll
      for (int r = 0; r < 4; ++r) {
        int row = bm + wm + i*16 + fq*4 + r;
        if (OUT_BF16)
          ((unsigned short*)Cout)[(size_t)row * N + col] = f2us(acc[i][j][r]);
        else
          ((float*)Cout)[(size_t)row * N + col] = acc[i][j][r];
      }
    }
  }
}

// ---------------- fp32 tiled NT GEMM (fallback path only) ----------------
__device__ inline void loadA4(const float* p, float* d) {
  float4 v = *(const float4*)p; d[0]=v.x; d[1]=v.y; d[2]=v.z; d[3]=v.w;
}
__device__ inline void loadA4(const unsigned short* p, float* d) {
  ushort4 v = *(const ushort4*)p;
  d[0]=us2f(v.x); d[1]=us2f(v.y); d[2]=us2f(v.z); d[3]=us2f(v.w);
}
__device__ inline void store8(float* C, size_t off, const float* v) {
  *(float4*)(C + off)     = make_float4(v[0], v[1], v[2], v[3]);
  *(float4*)(C + off + 4) = make_float4(v[4], v[5], v[6], v[7]);
}
__device__ inline void store8(unsigned short* C, size_t off, const float* v) {
  ushort4 a; a.x=f2us(v[0]); a.y=f2us(v[1]); a.z=f2us(v[2]); a.w=f2us(v[3]);
  ushort4 b; b.x=f2us(v[4]); b.y=f2us(v[5]); b.z=f2us(v[6]); b.w=f2us(v[7]);
  *(ushort4*)(C + off) = a; *(ushort4*)(C + off + 4) = b;
}

template<typename AT, typename OT>
__global__ __launch_bounds__(256) void gemm_nt(
    const AT* __restrict__ A, const float* __restrict__ Bw,
    OT* __restrict__ C, int M, int N, int K) {
  __shared__ float As[16][128+4];
  __shared__ float Bs[16][128+4];
  const int bm = blockIdx.y * 128;
  const int bn = blockIdx.x * 128;
  const int tid = threadIdx.x;
  const int tx = tid & 15, ty = tid >> 4;

  float acc[8][8];
  #pragma unroll
  for (int i = 0; i < 8; ++i)
    #pragma unroll
    for (int j = 0; j < 8; ++j) acc[i][j] = 0.f;

  for (int k0 = 0; k0 < K; k0 += 16) {
    #pragma unroll
    for (int r = 0; r < 2; ++r) {
      int i = tid + r * 256;
      int m  = i >> 2;
      int kv = (i & 3) << 2;
      float va[4];
      loadA4(A + (size_t)(bm + m) * K + k0 + kv, va);
      As[kv+0][m] = va[0]; As[kv+1][m] = va[1]; As[kv+2][m] = va[2]; As[kv+3][m] = va[3];
      float vb[4] = {0.f, 0.f, 0.f, 0.f};
      if (bn + m < N) loadA4(Bw + (size_t)(bn + m) * K + k0 + kv, vb);
      Bs[kv+0][m] = vb[0]; Bs[kv+1][m] = vb[1]; Bs[kv+2][m] = vb[2]; Bs[kv+3][m] = vb[3];
    }
    __syncthreads();
    #pragma unroll
    for (int kk = 0; kk < 16; ++kk) {
      float ra[8], rb[8];
      *(float4*)&ra[0] = *(const float4*)&As[kk][ty*8];
      *(float4*)&ra[4] = *(const float4*)&As[kk][ty*8+4];
      *(float4*)&rb[0] = *(const float4*)&Bs[kk][tx*8];
      *(float4*)&rb[4] = *(const float4*)&Bs[kk][tx*8+4];
      #pragma unroll
      for (int i = 0; i < 8; ++i)
        #pragma unroll
        for (int j = 0; j < 8; ++j) acc[i][j] += ra[i] * rb[j];
    }
    __syncthreads();
  }
  #pragma unroll
  for (int i = 0; i < 8; ++i) {
    int m  = bm + ty*8 + i;
    int n0 = bn + tx*8;
    if (n0 < N) store8(C, (size_t)m * N + n0, &acc[i][0]);
  }
}

// ---------------- dt GEMM (fp32, tiled) ----------------
__global__ __launch_bounds__(256) void dt_gemm(
    const float* __restrict__ x, const float* __restrict__ W,
    float* __restrict__ dtr) {
  __shared__ float sX[32][64];   // [kk][token]
  __shared__ float sW[32][64];   // [kk][head]
  const int tid = threadIdx.x;
  const int t0 = blockIdx.x * 64;
  const int tx = tid & 15;
  const int ty = tid >> 4;
  const float* Wdt = W + (size_t)NPROJ * DMODEL;

  float acc[4][4];
  #pragma unroll
  for (int i = 0; i < 4; ++i)
    #pragma unroll
    for (int j = 0; j < 4; ++j) acc[i][j] = 0.f;

  const int r  = tid >> 3;
  const int kq = (tid & 7) * 4;

  for (int k0 = 0; k0 < DMODEL; k0 += 32) {
    __syncthreads();
    #pragma unroll
    for (int rr = 0; rr < 2; ++rr) {
      int t = r + rr * 32;
      float4 v = *(const float4*)(x + (size_t)(t0 + t) * DMODEL + k0 + kq);
      sX[kq+0][t] = v.x; sX[kq+1][t] = v.y; sX[kq+2][t] = v.z; sX[kq+3][t] = v.w;
    }
    #pragma unroll
    for (int rr = 0; rr < 2; ++rr) {
      int hh = r + rr * 32;
      float4 v = *(const float4*)(Wdt + (size_t)hh * DMODEL + k0 + kq);
      sW[kq+0][hh] = v.x; sW[kq+1][hh] = v.y; sW[kq+2][hh] = v.z; sW[kq+3][hh] = v.w;
    }
    __syncthreads();
    #pragma unroll
    for (int kk = 0; kk < 32; ++kk) {
      float4 ra = *(const float4*)&sX[kk][ty*4];
      float4 rb = *(const float4*)&sW[kk][tx*4];
      float a[4] = {ra.x, ra.y, ra.z, ra.w};
      float b[4] = {rb.x, rb.y, rb.z, rb.w};
      #pragma unroll
      for (int i = 0; i < 4; ++i)
        #pragma unroll
        for (int j = 0; j < 4; ++j)
          acc[i][j] += a[i] * b[j];
    }
  }
  #pragma unroll
  for (int i = 0; i < 4; ++i) {
    float4 o = make_float4(acc[i][0], acc[i][1], acc[i][2], acc[i][3]);
    *(float4*)(dtr + (size_t)(t0 + ty*4 + i) * NHEADS + tx*4) = o;
  }
}

// ================= split-scan path =================
__global__ __launch_bounds__(256) void bc_conv_g(
    const unsigned short* __restrict__ proj, const float* __restrict__ cw,
    const float* __restrict__ cb, unsigned short* __restrict__ bcact,
    float* __restrict__ gbuf) {
  const int c = blockIdx.x & 31;
  const int b = blockIdx.x >> 5;
  const int tid = threadIdx.x;
  const int t0 = b * SEQ + c * CHUNK;
  __shared__ unsigned short sB[64*130];
  __shared__ unsigned short sC[64*130];
  for (int i = tid; i < 64*256; i += 256) {
    int s = i >> 8, ch = i & 255;
    int cx = 4096 + ch;
    int lb = c * CHUNK + s;
    float acc = cb[cx];
    #pragma unroll
    for (int j = 0; j < 4; ++j) {
      int ll = lb - 3 + j;
      if (ll >= 0)
        acc += cw[cx*4 + j] * us2f(proj[(size_t)(b*SEQ + ll) * NPROJ + DINNER + cx]);
    }
    float v = acc / (1.f + expf(-acc));
    unsigned short uv = f2us(v);
    if (ch < 128) sB[s*130 + ch] = uv;
    else          sC[s*130 + (ch - 128)] = uv;
    bcact[(size_t)(t0 + s) * 256 + ch] = uv;
  }
  __syncthreads();
  const int l = tid >> 2, q = tid & 3;
  float g[16];
  #pragma unroll
  for (int j = 0; j < 16; ++j) g[j] = 0.f;
  const uint32_t* Cu = (const uint32_t*)&sC[l * 130];
  for (int u = 0; u < 64; ++u) {
    uint32_t cv = Cu[u];
    float c0 = plo(cv), c1 = phi(cv);
    #pragma unroll
    for (int j = 0; j < 16; ++j) {
      uint32_t bv = ((const uint32_t*)&sB[(q*16 + j) * 130])[u];
      g[j] += c0 * plo(bv) + c1 * phi(bv);
    }
  }
  float* gr = gbuf + ((size_t)(b*NCHUNK + c)) * 4096 + l*64 + q*16;
  #pragma unroll
  for (int j = 0; j < 16; ++j) gr[j] = g[j];
}

// ---- A2 (MFMA) ----
__global__ __launch_bounds__(256, 4) void ssd_phase_a2_mfma(
    const unsigned short* __restrict__ proj, const unsigned short* __restrict__ bcact,
    const float* __restrict__ dtr, const float* __restrict__ cw,
    const float* __restrict__ cb, const float* __restrict__ A_log,
    const float* __restrict__ dt_bias, const float* __restrict__ gbuf,
    const float* __restrict__ Dv,
    unsigned short* __restrict__ cs, float* __restrict__ acs,
    unsigned short* __restrict__ yscan) {
  const int h = blockIdx.x & 63;
  const int c = (blockIdx.x >> 6) & 31;
  const int b = blockIdx.x >> 11;
  const int tid = threadIdx.x;
  const int t0 = b * SEQ + c * CHUNK;
  const int lane = tid & 63, wave = tid >> 6;
  const int fr = lane & 15, fq = lane >> 4;

  __shared__ __align__(16) unsigned short sBt[128*72];
  __shared__ __align__(16) unsigned short sXh[64*72];
  __shared__ __align__(16) unsigned short sW[64*72];
  __shared__ float sdt[64], sAc[64], sdecay[64];

  const float Ah = -expf(A_log[h]);
  if (tid < 64) {
    float raw = dtr[(size_t)(t0 + tid) * NHEADS + h] + dt_bias[h];
    float dt = (raw > 20.f) ? raw : log1pf(expf(raw));
    sdt[tid] = dt;
    float v = dt * Ah;
    #pragma unroll
    for (int off = 1; off < 64; off <<= 1) {
      float o = __shfl_up(v, off, 64);
      if (tid >= off) v += o;
    }
    sAc[tid] = v;
    float alast = __shfl(v, 63, 64);
    sdecay[tid] = expf(alast - v);
    acs[((size_t)((b*NHEADS + h)*NCHUNK + c))*64 + tid] = v;
  }
  __syncthreads();
  for (int i = tid; i < 64*128; i += 256) {
    int s = i >> 7, n = i & 127;
    float v = us2f(bcact[(size_t)(t0 + s) * 256 + n]) * sdt[s] * sdecay[s];
    sBt[n*72 + s] = f2us(v);
  }
  for (int i = tid; i < 64*64; i += 256) {
    int s = i >> 6, p = i & 63;
    int cx = h * HEADDIM + p;
    int lb = c * CHUNK + s;
    float acc = cb[cx];
    #pragma unroll
    for (int j = 0; j < 4; ++j) {
      int ll = lb - 3 + j;
      if (ll >= 0)
        acc += cw[cx*4 + j] * us2f(proj[(size_t)(b*SEQ + ll) * NPROJ + DINNER + cx]);
    }
    float xh = acc / (1.f + expf(-acc));
    sXh[p*72 + s] = f2us(xh);
  }
  {
    const float* gr = gbuf + ((size_t)(b*NCHUNK + c)) * 4096;
    for (int i = tid; i < 4096; i += 256) {
      int l = i >> 6, s = i & 63;
      float w = (s <= l) ? gr[i] * expf(sAc[l] - sAc[s]) * sdt[s] : 0.f;
      sW[l*72 + s] = f2us(w);
    }
  }
  __syncthreads();

  floatx4 accy[4];
  #pragma unroll
  for (int j = 0; j < 4; ++j) accy[j] = (floatx4){0.f, 0.f, 0.f, 0.f};
  #pragma unroll
  for (int k0 = 0; k0 < 64; k0 += 32) {
    short8 af = *(const short8*)(sW + (wave*16 + fr)*72 + k0 + fq*8);
    #pragma unroll
    for (int j = 0; j < 4; ++j) {
      short8 bf = *(const short8*)(sXh + (j*16 + fr)*72 + k0 + fq*8);
      accy[j] = __builtin_amdgcn_mfma_f32_16x16x32_bf16(af, bf, accy[j], 0, 0, 0);
    }
  }
  const float Dh = Dv[h];
  #pragma unroll
  for (int j = 0; j < 4; ++j) {
    int p = j*16 + fr;
    #pragma unroll
    for (int r = 0; r < 4; ++r) {
      int l = wave*16 + fq*4 + r;
      float yd = accy[j][r] + us2f(sXh[p*72 + l]) * Dh;
      yscan[(size_t)(t0 + l) * DINNER + h*HEADDIM + p] = f2us(yd);
    }
  }
  floatx4 accs[8];
  #pragma unroll
  for (int j = 0; j < 8; ++j) accs[j] = (floatx4){0.f, 0.f, 0.f, 0.f};
  #pragma unroll
  for (int k0 = 0; k0 < 64; k0 += 32) {
    short8 af = *(const short8*)(sXh + (wave*16 + fr)*72 + k0 + fq*8);
    #pragma unroll
    for (int j = 0; j < 8; ++j) {
      short8 bf = *(const short8*)(sBt + (j*16 + fr)*72 + k0 + fq*8);
      accs[j] = __builtin_amdgcn_mfma_f32_16x16x32_bf16(af, bf, accs[j], 0, 0, 0);
    }
  }
  const size_t csb = ((size_t)((b*NHEADS + h)*NCHUNK + c)) * (HEADDIM*DSTATE);
  #pragma unroll
  for (int j = 0; j < 8; ++j) {
    int n = j*16 + fr;
    #pragma unroll
    for (int r = 0; r < 4; ++r) {
      int p = wave*16 + fq*4 + r;
      cs[csb + p*128 + n] = f2us(accs[j][r]);
    }
  }
}

// ---- B: inter-chunk running-state scan ----
__global__ __launch_bounds__(256) void ssd_scan_states(
    unsigned short* __restrict__ cs, const float* __restrict__ acs) {
  int idx = blockIdx.x * 256 + threadIdx.x;
  int e  = idx & 8191;
  int bh = idx >> 13;
  float S = 0.f;
  for (int c = 0; c < NCHUNK; ++c) {
    float al = acs[((size_t)bh*NCHUNK + c)*64 + 63];
    size_t o = ((size_t)bh*NCHUNK + c)*(HEADDIM*DSTATE) + e;
    S = S * expf(al) + us2f(cs[o]);
    cs[o] = f2us(S);
  }
}

// ---- C (MFMA) ----
__global__ __launch_bounds__(256, 4) void ssd_phase_c_mfma(
    const unsigned short* __restrict__ bcact, const unsigned short* __restrict__ cs,
    const float* __restrict__ acs, unsigned short* __restrict__ yscan) {
  const int h = blockIdx.x & 63;
  const int c = (blockIdx.x >> 6) & 31;
  const int b = blockIdx.x >> 11;
  const int tid = threadIdx.x;
  const int t0 = b * SEQ + c * CHUNK;
  const int lane = tid & 63, wave = tid >> 6;
  const int fr = lane & 15, fq = lane >> 4;

  __shared__ __align__(16) unsigned short sC[64*136];
  __shared__ __align__(16) unsigned short sS[64*136];
  __shared__ float seAc[64];

  const size_t csb = ((size_t)((b*NHEADS + h)*NCHUNK + c)) * (HEADDIM*DSTATE);
  for (int i = tid; i < 8192; i += 256) {
    int p = i >> 7, n = i & 127;
    sS[p*136 + n] = cs[csb + i];
  }
  for (int i = tid; i < 8192; i += 256) {
    int l = i >> 7, n = i & 127;
    sC[l*136 + n] = bcact[(size_t)(t0 + l) * 256 + 128 + n];
  }
  if (tid < 64) seAc[tid] = expf(acs[((size_t)((b*NHEADS + h)*NCHUNK + c))*64 + tid]);
  __syncthreads();

  floatx4 acc[4];
  #pragma unroll
  for (int j = 0; j < 4; ++j) acc[j] = (floatx4){0.f, 0.f, 0.f, 0.f};
  #pragma unroll
  for (int k0 = 0; k0 < 128; k0 += 32) {
    short8 af = *(const short8*)(sC + (wave*16 + fr)*136 + k0 + fq*8);
    #pragma unroll
    for (int j = 0; j < 4; ++j) {
      short8 bf = *(const short8*)(sS + (j*16 + fr)*136 + k0 + fq*8);
      acc[j] = __builtin_amdgcn_mfma_f32_16x16x32_bf16(af, bf, acc[j], 0, 0, 0);
    }
  }
  #pragma unroll
  for (int j = 0; j < 4; ++j) {
    int p = j*16 + fr;
    #pragma unroll
    for (int r = 0; r < 4; ++r) {
      int l = wave*16 + fq*4 + r;
      size_t yi = (size_t)(t0 + l) * DINNER + h*HEADDIM + p;
      yscan[yi] = f2us(us2f(yscan[yi]) + acc[j][r] * seAc[l]);
    }
  }
}

__global__ __launch_bounds__(256) void gate_rmsnorm2(
    const unsigned short* __restrict__ proj, const float* __restrict__ norm_w,
    unsigned short* __restrict__ yscan) {
  const int t = blockIdx.x;
  const int tid = threadIdx.x;
  __shared__ float ybuf[DINNER];
  __shared__ float wpart[4];
  __shared__ float sinv;
  float ss = 0.f;
  for (int i = tid; i < DINNER; i += 256) {
    float zv = us2f(proj[(size_t)t * NPROJ + i]);
    float yv = us2f(yscan[(size_t)t * DINNER + i]) * (zv / (1.f + expf(-zv)));
    ybuf[i] = yv;
    ss += yv * yv;
  }
  #pragma unroll
  for (int off = 32; off > 0; off >>= 1) ss += __shfl_down(ss, off, 64);
  if ((tid & 63) == 0) wpart[tid >> 6] = ss;
  __syncthreads();
  if (tid == 0) {
    float tot = wpart[0] + wpart[1] + wpart[2] + wpart[3];
    sinv = 1.f / sqrtf(tot / (float)DINNER + 1e-5f);
  }
  __syncthreads();
  float inv = sinv;
  for (int i = tid; i < DINNER; i += 256)
    yscan[(size_t)t * DINNER + i] = f2us(ybuf[i] * inv * norm_w[i]);
}

// ================= FALLBACK path =================
__global__ __launch_bounds__(512) void ssd_fused(
    const unsigned short* __restrict__ proj, const float* __restrict__ dtr,
    const float* __restrict__ cw, const float* __restrict__ cb,
    const float* __restrict__ A_log, const float* __restrict__ dt_bias,
    unsigned short* __restrict__ yscan) {
  const int h = blockIdx.x & 63;
  const int b = blockIdx.x >> 6;
  const int tid = threadIdx.x;

  __shared__ unsigned short sB[64*130];
  __shared__ unsigned short sC[64*130];
  __shared__ unsigned short sX[64*66];
  __shared__ float sW[64*65];
  __shared__ float sdt[64], sAc[64], sdecay[64], seAc[64];

  const float Ah = -expf(A_log[h]);
  const float dbias = dt_bias[h];

  float S[16];
  #pragma unroll
  for (int j = 0; j < 16; ++j) S[j] = 0.f;

  const int lG  = tid >> 3;
  const int oc  = tid & 7;

  for (int c = 0; c < NCHUNK; ++c) {
    const int t0 = b * SEQ + c * CHUNK;
    __syncthreads();
    if (tid < 64) {
      float raw = dtr[(size_t)(t0 + tid) * NHEADS + h] + dbias;
      sdt[tid] = (raw > 20.f) ? raw : log1pf(expf(raw));
    }
    for (int i = tid; i < 64*256; i += 512) {
      int s = i >> 8, ch = i & 255;
      int cx = 4096 + ch;
      int lb = c * CHUNK + s;
      float acc = cb[cx];
      #pragma unroll
      for (int j = 0; j < 4; ++j) {
        int ll = lb - 3 + j;
        if (ll >= 0)
          acc += cw[cx*4 + j] * us2f(proj[(size_t)(b*SEQ + ll) * NPROJ + DINNER + cx]);
      }
      float v = acc / (1.f + expf(-acc));
      if (ch < 128) sB[s*130 + ch] = f2us(v);
      else          sC[s*130 + (ch - 128)] = f2us(v);
    }
    __syncthreads();
    if (tid == 0) {
      float run = 0.f;
      for (int s = 0; s < CHUNK; ++s) { run += sdt[s] * Ah; sAc[s] = run; }
    }
    __syncthreads();
    if (tid < 64) {
      float last = sAc[63];
      sdecay[tid] = expf(last - sAc[tid]);
      seAc[tid]   = expf(sAc[tid]);
    }
    for (int i = tid; i < 64*64; i += 512) {
      int s = i >> 6, p = i & 63;
      int cx = h * HEADDIM + p;
      int lb = c * CHUNK + s;
      float acc = cb[cx];
      #pragma unroll
      for (int j = 0; j < 4; ++j) {
        int ll = lb - 3 + j;
        if (ll >= 0)
          acc += cw[cx*4 + j] * us2f(proj[(size_t)(b*SEQ + ll) * NPROJ + DINNER + cx]);
      }
      float v = acc / (1.f + expf(-acc));
      sX[s*66 + p] = f2us(v * sdt[s]);
    }
    __syncthreads();

    float g[8];
    #pragma unroll
    for (int j = 0; j < 8; ++j) g[j] = 0.f;
    {
      const uint32_t* Cu = (const uint32_t*)&sC[lG * 130];
      for (int u = 0; u < 64; ++u) {
        uint32_t cv = Cu[u];
        float c0 = plo(cv), c1 = phi(cv);
        #pragma unroll
        for (int j = 0; j < 8; ++j) {
          uint32_t bv = ((const uint32_t*)&sB[(oc*8 + j) * 130])[u];
          g[j] += c0 * plo(bv) + c1 * phi(bv);
        }
      }
    }
    {
      float acl = sAc[lG];
      #pragma unroll
      for (int j = 0; j < 8; ++j) {
        int s = oc*8 + j;
        sW[lG*65 + s] = (s <= lG) ? g[j] * expf(acl - sAc[s]) : 0.f;
      }
    }
    {
      float elast = expf(sAc[63]);
      #pragma unroll
      for (int j = 0; j < 16; ++j) S[j] *= elast;
      for (int s = 0; s < CHUNK; ++s) {
        float w = sdecay[s] * us2f(sX[s*66 + lG]);
        const uint32_t* Bu = (const uint32_t*)&sB[s*130 + oc*16];
        #pragma unroll
        for (int ju = 0; ju < 8; ++ju) {
          uint32_t bv = Bu[ju];
          S[2*ju]   += plo(bv) * w;
          S[2*ju+1] += phi(bv) * w;
        }
      }
    }
    __syncthreads();
    #pragma unroll
    for (int j = 0; j < 16; ++j) sB[lG*130 + oc*16 + j] = f2us(S[j]);
    __syncthreads();
    for (int o = tid; o < CHUNK*HEADDIM; o += 512) {
      int l = o >> 6, p = o & 63;
      float yd = 0.f;
      for (int s = 0; s <= l; ++s)
        yd += sW[l*65 + s] * us2f(sX[s*66 + p]);
      float yo = 0.f;
      const uint32_t* Cu = (const uint32_t*)&sC[l * 130];
      const uint32_t* Su = (const uint32_t*)&sB[p * 130];
      for (int u = 0; u < 64; ++u) {
        uint32_t cv = Cu[u], sv = Su[u];
        yo += plo(cv) * plo(sv) + phi(cv) * phi(sv);
      }
      float y = yd + yo * seAc[l];
      yscan[(size_t)(t0 + l) * DINNER + h * HEADDIM + p] = f2us(y);
    }
  }
}

__global__ __launch_bounds__(256) void gate_rmsnorm_dskip(
    const unsigned short* __restrict__ proj, const float* __restrict__ cw,
    const float* __restrict__ cb, const float* __restrict__ Dv,
    const float* __restrict__ norm_w, unsigned short* __restrict__ yscan) {
  const int t = blockIdx.x;
  const int tid = threadIdx.x;
  const int b = t >> 11, lb = t & 2047;
  __shared__ float ybuf[DINNER];
  __shared__ float wpart[4];
  __shared__ float sinv;
  float ss = 0.f;
  for (int i = tid; i < DINNER; i += 256) {
    float zv = us2f(proj[(size_t)t * NPROJ + i]);
    float acc = cb[i];
    #pragma unroll
    for (int j = 0; j < 4; ++j) {
      int ll = lb - 3 + j;
      if (ll >= 0)
        acc += cw[i*4 + j] * us2f(proj[(size_t)(b*SEQ + ll) * NPROJ + DINNER + i]);
    }
    float xh = acc / (1.f + expf(-acc));
    float yv = us2f(yscan[(size_t)t * DINNER + i]) + xh * Dv[i >> 6];
    yv = yv * (zv / (1.f + expf(-zv)));
    ybuf[i] = yv;
    ss += yv * yv;
  }
  #pragma unroll
  for (int off = 32; off > 0; off >>= 1) ss += __shfl_down(ss, off, 64);
  if ((tid & 63) == 0) wpart[tid >> 6] = ss;
  __syncthreads();
  if (tid == 0) {
    float tot = wpart[0] + wpart[1] + wpart[2] + wpart[3];
    sinv = 1.f / sqrtf(tot / (float)DINNER + 1e-5f);
  }
  __syncthreads();
  float inv = sinv;
  for (int i = tid; i < DINNER; i += 256)
    yscan[(size_t)t * DINNER + i] = f2us(ybuf[i] * inv * norm_w[i]);
}

// ---------------- launch ----------------
extern "C" void kernel_launch(void* const* d_in, const int* in_sizes, int n_in,
                              void* d_out, int out_size, void* d_ws, size_t ws_size,
                              hipStream_t stream) {
  const float* x          = (const float*)d_in[0];
  const float* in_proj_w  = (const float*)d_in[1];
  const float* conv_w     = (const float*)d_in[2];
  const float* conv_b     = (const float*)d_in[3];
  const float* A_log      = (const float*)d_in[4];
  const float* Dv         = (const float*)d_in[5];
  const float* dt_bias    = (const float*)d_in[6];
  const float* norm_w     = (const float*)d_in[7];
  const float* out_proj_w = (const float*)d_in[8];
  float* out = (float*)d_out;

  unsigned short* proj  = (unsigned short*)d_ws;
  float*          dtr   = (float*)(proj + (size_t)TOKENS * NPROJ);
  unsigned short* yscan = (unsigned short*)(dtr + (size_t)TOKENS * NHEADS);
  unsigned short* cs    = yscan + (size_t)TOKENS * DINNER;
  float*          acs   = (float*)(cs + (size_t)B_SZ*NHEADS*NCHUNK*HEADDIM*DSTATE);
  unsigned short* bcact = (unsigned short*)(acs + (size_t)B_SZ*NHEADS*NCHUNK*64);
  float*          gbuf  = (float*)(bcact + (size_t)TOKENS*256);
  const size_t NEEDED = (size_t)((char*)(gbuf + (size_t)B_SZ*NCHUNK*4096) - (char*)d_ws);

  unsigned short* xb  = cs;                                  // TOKENS*DMODEL
  unsigned short* wib = xb + (size_t)TOKENS * DMODEL;        // NPROJ*DMODEL
  unsigned short* wob = proj;                                // DMODEL*DINNER

  if (ws_size >= NEEDED) {
    cast_f32_bf16<<<(TOKENS*DMODEL)/1024, 256, 0, stream>>>(x, xb, TOKENS*DMODEL);
    cast_f32_bf16<<<((size_t)NPROJ*DMODEL)/1024, 256, 0, stream>>>(in_proj_w, wib, NPROJ*DMODEL);
    {
      dim3 grid(NPROJ/256, TOKENS/256);
      gemm_bt_256<1><<<grid, 512, 0, stream>>>(xb, wib, proj, TOKENS, NPROJ, DMODEL);
    }
    dt_gemm<<<TOKENS/64, 256, 0, stream>>>(x, in_proj_w, dtr);
    bc_conv_g<<<B_SZ*NCHUNK, 256, 0, stream>>>(proj, conv_w, conv_b, bcact, gbuf);
    ssd_phase_a2_mfma<<<B_SZ*NCHUNK*NHEADS, 256, 0, stream>>>(
        proj, bcact, dtr, conv_w, conv_b, A_log, dt_bias, gbuf, Dv, cs, acs, yscan);
    ssd_scan_states<<<(B_SZ*NHEADS*HEADDIM*DSTATE)/256, 256, 0, stream>>>(cs, acs);
    ssd_phase_c_mfma<<<B_SZ*NCHUNK*NHEADS, 256, 0, stream>>>(bcact, cs, acs, yscan);
    gate_rmsnorm2<<<TOKENS, 256, 0, stream>>>(proj, norm_w, yscan);
    cast_f32_bf16<<<((size_t)DMODEL*DINNER)/1024, 256, 0, stream>>>(out_proj_w, wob, DMODEL*DINNER);
    {
      dim3 grid(DMODEL/128, TOKENS/128);
      gemm_bt_mfma<0><<<grid, 256, 0, stream>>>(yscan, wob, out, TOKENS, DMODEL, DINNER);
    }
  } else {
    {
      dim3 grid(NPROJ/128, TOKENS/128);
      gemm_nt<float, unsigned short><<<grid, 256, 0, stream>>>(
          x, in_proj_w, proj, TOKENS, NPROJ, DMODEL);
    }
    dt_gemm<<<TOKENS/64, 256, 0, stream>>>(x, in_proj_w, dtr);
    ssd_fused<<<B_SZ*NHEADS, 512, 0, stream>>>(proj, dtr, conv_w, conv_b,
                                               A_log, dt_bias, yscan);
    gate_rmsnorm_dskip<<<TOKENS, 256, 0, stream>>>(proj, conv_w, conv_b, Dv, norm_w, yscan);
    {
      dim3 grid(DMODEL/128, TOKENS/128);
      gemm_nt<unsigned short, float><<<grid, 256, 0, stream>>>(
          yscan, out_proj_w, out, TOKENS, DMODEL, DINNER);
    }
  }
}

// Round 3
// 795.984 us; speedup vs baseline: 1.2313x; 1.0669x over previous
//
#include <hip/hip_runtime.h>
#include <cstddef>
#include <cstdint>

// ---------------- problem constants ----------------
#define B_SZ    2
#define SEQ     2048
#define DMODEL  2048
#define DINNER  4096
#define DSTATE  128
#define NHEADS  64
#define HEADDIM 64
#define DXBC    4352          // DINNER + 2*DSTATE
#define NPROJ   8448          // DINNER + DXBC (z | xBC); dt handled separately in fp32
#define CHUNK   64
#define NCHUNK  32
#define TOKENS  (B_SZ*SEQ)    // 4096

typedef __attribute__((ext_vector_type(8))) short short8;   // 8 x bf16
typedef __attribute__((ext_vector_type(4))) float floatx4;

// ---- bf16 <-> f32 helpers ----
__device__ inline float us2f(unsigned short u) {
  union { uint32_t i; float f; } c; c.i = ((uint32_t)u) << 16; return c.f;
}
__device__ inline unsigned short f2us(float f) {
  union { float f; uint32_t i; } c; c.f = f;
  uint32_t r = (c.i + 0x7fffu + ((c.i >> 16) & 1u)) >> 16;
  return (unsigned short)r;
}
__device__ inline float plo(uint32_t v) {
  union { uint32_t i; float f; } c; c.i = v << 16; return c.f;
}
__device__ inline float phi(uint32_t v) {
  union { uint32_t i; float f; } c; c.i = v & 0xffff0000u; return c.f;
}

// ---------------- f32 -> bf16 cast (vectorized) ----------------
__global__ __launch_bounds__(256) void cast_f32_bf16(
    const float* __restrict__ src, unsigned short* __restrict__ dst, int n) {
  int i = (blockIdx.x * 256 + threadIdx.x) * 4;
  if (i < n) {
    float4 v = *(const float4*)(src + i);
    ushort4 o;
    o.x = f2us(v.x); o.y = f2us(v.y); o.z = f2us(v.z); o.w = f2us(v.w);
    *(ushort4*)(dst + i) = o;
  }
}

// ======= pipelined MFMA bf16 NT GEMM: C[M,N] = A[M,K] @ B[N,K]^T ============
// BM=128, BN=256, 256 threads (4 waves, 1M x 4N), per-wave out 128x64.
// K advanced in 32-wide halves. LDS = ring of 3 half-buffers (24KB each:
// A 128x32 | B 256x32) -> 72KB -> 2 blocks/CU. Depth-2 prefetch with COUNTED
// vmcnt(6) at each phase end (never 0 in main loop). Explicit lgkmcnt(0)
// before each raw s_barrier so ring reuse can't race ds_reads.
// Bank swizzle for 64B rows: 16B-slot ^= (row>>1)&3, applied both-sides
// (pre-swizzled global source for global_load_lds + swizzled ds_read).
// XCD-aware bijective blockIdx remap (nwg % 8 == 0 for both call sites).
template<int OUT_BF16>
__global__ __launch_bounds__(256, 2) void gemm_bt_p3(
    const unsigned short* __restrict__ A, const unsigned short* __restrict__ B,
    void* __restrict__ Cout, int M, int N, int K, int GM) {
  __shared__ __align__(16) unsigned short sT[3 * 12288];  // 3 x (A 4096 | B 8192)
  const int tid  = threadIdx.x;
  const int lane = tid & 63;
  const int wc   = tid >> 6;        // wave 0..3 = N quadrant
  const int fr   = lane & 15;
  const int fq   = lane >> 4;

  // XCD-aware remap (contiguous wgid chunk per XCD; wgid -> (tm, tn) M-major
  // so consecutive wgid share the B panel)
  const int nwg  = gridDim.x;
  int wgid = blockIdx.x;
  if ((nwg & 7) == 0) wgid = (wgid & 7) * (nwg >> 3) + (wgid >> 3);
  const int bm = (wgid % GM) * 128;
  const int bn = (wgid / GM) * 256;

  floatx4 acc[8][4];
  #pragma unroll
  for (int i = 0; i < 8; ++i)
    #pragma unroll
    for (int j = 0; j < 4; ++j) acc[i][j] = (floatx4){0.f, 0.f, 0.f, 0.f};

  // stage one 32-wide half-K into ring buffer rb: 6 x 16B loads per thread.
  // chunks 0..1 = A (128 rows x 4 slots), 2..5 = B (256 rows x 4 slots).
  auto stage = [&](int rb, int kb) {
    unsigned short* dst = (unsigned short*)sT + rb * 12288;
    #pragma unroll
    for (int q = 0; q < 6; ++q) {
      if (q < 2) {
        int i = q * 256 + tid;
        int row = i >> 2, slot = i & 3;
        const unsigned short* g =
            A + (size_t)(bm + row) * K + kb + 8 * (slot ^ ((row >> 1) & 3));
        __builtin_amdgcn_global_load_lds(
            (const __attribute__((address_space(1))) uint32_t*)g,
            (__attribute__((address_space(3))) uint32_t*)(dst + i * 8), 16, 0, 0);
      } else {
        int i = (q - 2) * 256 + tid;
        int row = i >> 2, slot = i & 3;
        const unsigned short* g =
            B + (size_t)(bn + row) * K + kb + 8 * (slot ^ ((row >> 1) & 3));
        __builtin_amdgcn_global_load_lds(
            (const __attribute__((address_space(1))) uint32_t*)g,
            (__attribute__((address_space(3))) uint32_t*)(dst + 4096 + i * 8), 16, 0, 0);
      }
    }
  };

  const int NH = K >> 5;
  // prologue: halves 0,1 in flight; wait for half 0 only.
  stage(0, 0);
  stage(1, 32);
  asm volatile("s_waitcnt vmcnt(6)" ::: "memory");
  asm volatile("s_barrier" ::: "memory");

  int cb = 0, sb = 2;   // current ring idx, stage ring idx (h+2)
  for (int h = 0; h < NH; ++h) {
    const unsigned short* buf = (const unsigned short*)sT + cb * 12288;
    if (h + 2 < NH) stage(sb, (h + 2) << 5);

    short8 af[8], bf[4];
    #pragma unroll
    for (int i = 0; i < 8; ++i) {
      int row = i * 16 + fr;
      af[i] = *(const short8*)(buf + row * 32 + 8 * (fq ^ ((row >> 1) & 3)));
    }
    #pragma unroll
    for (int j = 0; j < 4; ++j) {
      int row = wc * 64 + j * 16 + fr;
      bf[j] = *(const short8*)(buf + 4096 + row * 32 + 8 * (fq ^ ((row >> 1) & 3)));
    }
    __builtin_amdgcn_s_setprio(1);
    #pragma unroll
    for (int i = 0; i < 8; ++i)
      #pragma unroll
      for (int j = 0; j < 4; ++j)
        acc[i][j] = __builtin_amdgcn_mfma_f32_16x16x32_bf16(af[i], bf[j], acc[i][j], 0, 0, 0);
    __builtin_amdgcn_s_setprio(0);

    if (h < NH - 2) asm volatile("s_waitcnt vmcnt(6) lgkmcnt(0)" ::: "memory");
    else            asm volatile("s_waitcnt vmcnt(0) lgkmcnt(0)" ::: "memory");
    asm volatile("s_barrier" ::: "memory");
    cb = (cb == 2) ? 0 : cb + 1;
    sb = (sb == 2) ? 0 : sb + 1;
  }

  // epilogue
  #pragma unroll
  for (int i = 0; i < 8; ++i) {
    #pragma unroll
    for (int j = 0; j < 4; ++j) {
      int col = bn + wc * 64 + j * 16 + fr;
      #pragma unroll
      for (int r = 0; r < 4; ++r) {
        int row = bm + i * 16 + fq * 4 + r;
        if (OUT_BF16)
          ((unsigned short*)Cout)[(size_t)row * N + col] = f2us(acc[i][j][r]);
        else
          ((float*)Cout)[(size_t)row * N + col] = acc[i][j][r];
      }
    }
  }
}

// ---------------- fp32 tiled NT GEMM (fallback path only) ----------------
__device__ inline void loadA4(const float* p, float* d) {
  float4 v = *(const float4*)p; d[0]=v.x; d[1]=v.y; d[2]=v.z; d[3]=v.w;
}
__device__ inline void loadA4(const unsigned short* p, float* d) {
  ushort4 v = *(const ushort4*)p;
  d[0]=us2f(v.x); d[1]=us2f(v.y); d[2]=us2f(v.z); d[3]=us2f(v.w);
}
__device__ inline void store8(float* C, size_t off, const float* v) {
  *(float4*)(C + off)     = make_float4(v[0], v[1], v[2], v[3]);
  *(float4*)(C + off + 4) = make_float4(v[4], v[5], v[6], v[7]);
}
__device__ inline void store8(unsigned short* C, size_t off, const float* v) {
  ushort4 a; a.x=f2us(v[0]); a.y=f2us(v[1]); a.z=f2us(v[2]); a.w=f2us(v[3]);
  ushort4 b; b.x=f2us(v[4]); b.y=f2us(v[5]); b.z=f2us(v[6]); b.w=f2us(v[7]);
  *(ushort4*)(C + off) = a; *(ushort4*)(C + off + 4) = b;
}

template<typename AT, typename OT>
__global__ __launch_bounds__(256) void gemm_nt(
    const AT* __restrict__ A, const float* __restrict__ Bw,
    OT* __restrict__ C, int M, int N, int K) {
  __shared__ float As[16][128+4];
  __shared__ float Bs[16][128+4];
  const int bm = blockIdx.y * 128;
  const int bn = blockIdx.x * 128;
  const int tid = threadIdx.x;
  const int tx = tid & 15, ty = tid >> 4;

  float acc[8][8];
  #pragma unroll
  for (int i = 0; i < 8; ++i)
    #pragma unroll
    for (int j = 0; j < 8; ++j) acc[i][j] = 0.f;

  for (int k0 = 0; k0 < K; k0 += 16) {
    #pragma unroll
    for (int r = 0; r < 2; ++r) {
      int i = tid + r * 256;
      int m  = i >> 2;
      int kv = (i & 3) << 2;
      float va[4];
      loadA4(A + (size_t)(bm + m) * K + k0 + kv, va);
      As[kv+0][m] = va[0]; As[kv+1][m] = va[1]; As[kv+2][m] = va[2]; As[kv+3][m] = va[3];
      float vb[4] = {0.f, 0.f, 0.f, 0.f};
      if (bn + m < N) loadA4(Bw + (size_t)(bn + m) * K + k0 + kv, vb);
      Bs[kv+0][m] = vb[0]; Bs[kv+1][m] = vb[1]; Bs[kv+2][m] = vb[2]; Bs[kv+3][m] = vb[3];
    }
    __syncthreads();
    #pragma unroll
    for (int kk = 0; kk < 16; ++kk) {
      float ra[8], rb[8];
      *(float4*)&ra[0] = *(const float4*)&As[kk][ty*8];
      *(float4*)&ra[4] = *(const float4*)&As[kk][ty*8+4];
      *(float4*)&rb[0] = *(const float4*)&Bs[kk][tx*8];
      *(float4*)&rb[4] = *(const float4*)&Bs[kk][tx*8+4];
      #pragma unroll
      for (int i = 0; i < 8; ++i)
        #pragma unroll
        for (int j = 0; j < 8; ++j) acc[i][j] += ra[i] * rb[j];
    }
    __syncthreads();
  }
  #pragma unroll
  for (int i = 0; i < 8; ++i) {
    int m  = bm + ty*8 + i;
    int n0 = bn + tx*8;
    if (n0 < N) store8(C, (size_t)m * N + n0, &acc[i][0]);
  }
}

// ---------------- dt GEMM (fp32, tiled) ----------------
__global__ __launch_bounds__(256) void dt_gemm(
    const float* __restrict__ x, const float* __restrict__ W,
    float* __restrict__ dtr) {
  __shared__ float sX[32][64];   // [kk][token]
  __shared__ float sW[32][64];   // [kk][head]
  const int tid = threadIdx.x;
  const int t0 = blockIdx.x * 64;
  const int tx = tid & 15;
  const int ty = tid >> 4;
  const float* Wdt = W + (size_t)NPROJ * DMODEL;

  float acc[4][4];
  #pragma unroll
  for (int i = 0; i < 4; ++i)
    #pragma unroll
    for (int j = 0; j < 4; ++j) acc[i][j] = 0.f;

  const int r  = tid >> 3;
  const int kq = (tid & 7) * 4;

  for (int k0 = 0; k0 < DMODEL; k0 += 32) {
    __syncthreads();
    #pragma unroll
    for (int rr = 0; rr < 2; ++rr) {
      int t = r + rr * 32;
      float4 v = *(const float4*)(x + (size_t)(t0 + t) * DMODEL + k0 + kq);
      sX[kq+0][t] = v.x; sX[kq+1][t] = v.y; sX[kq+2][t] = v.z; sX[kq+3][t] = v.w;
    }
    #pragma unroll
    for (int rr = 0; rr < 2; ++rr) {
      int hh = r + rr * 32;
      float4 v = *(const float4*)(Wdt + (size_t)hh * DMODEL + k0 + kq);
      sW[kq+0][hh] = v.x; sW[kq+1][hh] = v.y; sW[kq+2][hh] = v.z; sW[kq+3][hh] = v.w;
    }
    __syncthreads();
    #pragma unroll
    for (int kk = 0; kk < 32; ++kk) {
      float4 ra = *(const float4*)&sX[kk][ty*4];
      float4 rb = *(const float4*)&sW[kk][tx*4];
      float a[4] = {ra.x, ra.y, ra.z, ra.w};
      float b[4] = {rb.x, rb.y, rb.z, rb.w};
      #pragma unroll
      for (int i = 0; i < 4; ++i)
        #pragma unroll
        for (int j = 0; j < 4; ++j)
          acc[i][j] += a[i] * b[j];
    }
  }
  #pragma unroll
  for (int i = 0; i < 4; ++i) {
    float4 o = make_float4(acc[i][0], acc[i][1], acc[i][2], acc[i][3]);
    *(float4*)(dtr + (size_t)(t0 + ty*4 + i) * NHEADS + tx*4) = o;
  }
}

// ================= split-scan path =================
__global__ __launch_bounds__(256) void bc_conv_g(
    const unsigned short* __restrict__ proj, const float* __restrict__ cw,
    const float* __restrict__ cb, unsigned short* __restrict__ bcact,
    float* __restrict__ gbuf) {
  const int c = blockIdx.x & 31;
  const int b = blockIdx.x >> 5;
  const int tid = threadIdx.x;
  const int t0 = b * SEQ + c * CHUNK;
  __shared__ unsigned short sB[64*130];
  __shared__ unsigned short sC[64*130];
  for (int i = tid; i < 64*256; i += 256) {
    int s = i >> 8, ch = i & 255;
    int cx = 4096 + ch;
    int lb = c * CHUNK + s;
    float acc = cb[cx];
    #pragma unroll
    for (int j = 0; j < 4; ++j) {
      int ll = lb - 3 + j;
      if (ll >= 0)
        acc += cw[cx*4 + j] * us2f(proj[(size_t)(b*SEQ + ll) * NPROJ + DINNER + cx]);
    }
    float v = acc / (1.f + expf(-acc));
    unsigned short uv = f2us(v);
    if (ch < 128) sB[s*130 + ch] = uv;
    else          sC[s*130 + (ch - 128)] = uv;
    bcact[(size_t)(t0 + s) * 256 + ch] = uv;
  }
  __syncthreads();
  const int l = tid >> 2, q = tid & 3;
  float g[16];
  #pragma unroll
  for (int j = 0; j < 16; ++j) g[j] = 0.f;
  const uint32_t* Cu = (const uint32_t*)&sC[l * 130];
  for (int u = 0; u < 64; ++u) {
    uint32_t cv = Cu[u];
    float c0 = plo(cv), c1 = phi(cv);
    #pragma unroll
    for (int j = 0; j < 16; ++j) {
      uint32_t bv = ((const uint32_t*)&sB[(q*16 + j) * 130])[u];
      g[j] += c0 * plo(bv) + c1 * phi(bv);
    }
  }
  float* gr = gbuf + ((size_t)(b*NCHUNK + c)) * 4096 + l*64 + q*16;
  #pragma unroll
  for (int j = 0; j < 16; ++j) gr[j] = g[j];
}

// ---- A2 (MFMA) ----
__global__ __launch_bounds__(256, 4) void ssd_phase_a2_mfma(
    const unsigned short* __restrict__ proj, const unsigned short* __restrict__ bcact,
    const float* __restrict__ dtr, const float* __restrict__ cw,
    const float* __restrict__ cb, const float* __restrict__ A_log,
    const float* __restrict__ dt_bias, const float* __restrict__ gbuf,
    const float* __restrict__ Dv,
    unsigned short* __restrict__ cs, float* __restrict__ acs,
    unsigned short* __restrict__ yscan) {
  const int h = blockIdx.x & 63;
  const int c = (blockIdx.x >> 6) & 31;
  const int b = blockIdx.x >> 11;
  const int tid = threadIdx.x;
  const int t0 = b * SEQ + c * CHUNK;
  const int lane = tid & 63, wave = tid >> 6;
  const int fr = lane & 15, fq = lane >> 4;

  __shared__ __align__(16) unsigned short sBt[128*72];
  __shared__ __align__(16) unsigned short sXh[64*72];
  __shared__ __align__(16) unsigned short sW[64*72];
  __shared__ float sdt[64], sAc[64], sdecay[64];

  const float Ah = -expf(A_log[h]);
  if (tid < 64) {
    float raw = dtr[(size_t)(t0 + tid) * NHEADS + h] + dt_bias[h];
    float dt = (raw > 20.f) ? raw : log1pf(expf(raw));
    sdt[tid] = dt;
    float v = dt * Ah;
    #pragma unroll
    for (int off = 1; off < 64; off <<= 1) {
      float o = __shfl_up(v, off, 64);
      if (tid >= off) v += o;
    }
    sAc[tid] = v;
    float alast = __shfl(v, 63, 64);
    sdecay[tid] = expf(alast - v);
    acs[((size_t)((b*NHEADS + h)*NCHUNK + c))*64 + tid] = v;
  }
  __syncthreads();
  for (int i = tid; i < 64*128; i += 256) {
    int s = i >> 7, n = i & 127;
    float v = us2f(bcact[(size_t)(t0 + s) * 256 + n]) * sdt[s] * sdecay[s];
    sBt[n*72 + s] = f2us(v);
  }
  for (int i = tid; i < 64*64; i += 256) {
    int s = i >> 6, p = i & 63;
    int cx = h * HEADDIM + p;
    int lb = c * CHUNK + s;
    float acc = cb[cx];
    #pragma unroll
    for (int j = 0; j < 4; ++j) {
      int ll = lb - 3 + j;
      if (ll >= 0)
        acc += cw[cx*4 + j] * us2f(proj[(size_t)(b*SEQ + ll) * NPROJ + DINNER + cx]);
    }
    float xh = acc / (1.f + expf(-acc));
    sXh[p*72 + s] = f2us(xh);
  }
  {
    const float* gr = gbuf + ((size_t)(b*NCHUNK + c)) * 4096;
    for (int i = tid; i < 4096; i += 256) {
      int l = i >> 6, s = i & 63;
      float w = (s <= l) ? gr[i] * expf(sAc[l] - sAc[s]) * sdt[s] : 0.f;
      sW[l*72 + s] = f2us(w);
    }
  }
  __syncthreads();

  floatx4 accy[4];
  #pragma unroll
  for (int j = 0; j < 4; ++j) accy[j] = (floatx4){0.f, 0.f, 0.f, 0.f};
  #pragma unroll
  for (int k0 = 0; k0 < 64; k0 += 32) {
    short8 af = *(const short8*)(sW + (wave*16 + fr)*72 + k0 + fq*8);
    #pragma unroll
    for (int j = 0; j < 4; ++j) {
      short8 bf = *(const short8*)(sXh + (j*16 + fr)*72 + k0 + fq*8);
      accy[j] = __builtin_amdgcn_mfma_f32_16x16x32_bf16(af, bf, accy[j], 0, 0, 0);
    }
  }
  const float Dh = Dv[h];
  #pragma unroll
  for (int j = 0; j < 4; ++j) {
    int p = j*16 + fr;
    #pragma unroll
    for (int r = 0; r < 4; ++r) {
      int l = wave*16 + fq*4 + r;
      float yd = accy[j][r] + us2f(sXh[p*72 + l]) * Dh;
      yscan[(size_t)(t0 + l) * DINNER + h*HEADDIM + p] = f2us(yd);
    }
  }
  floatx4 accs[8];
  #pragma unroll
  for (int j = 0; j < 8; ++j) accs[j] = (floatx4){0.f, 0.f, 0.f, 0.f};
  #pragma unroll
  for (int k0 = 0; k0 < 64; k0 += 32) {
    short8 af = *(const short8*)(sXh + (wave*16 + fr)*72 + k0 + fq*8);
    #pragma unroll
    for (int j = 0; j < 8; ++j) {
      short8 bf = *(const short8*)(sBt + (j*16 + fr)*72 + k0 + fq*8);
      accs[j] = __builtin_amdgcn_mfma_f32_16x16x32_bf16(af, bf, accs[j], 0, 0, 0);
    }
  }
  const size_t csb = ((size_t)((b*NHEADS + h)*NCHUNK + c)) * (HEADDIM*DSTATE);
  #pragma unroll
  for (int j = 0; j < 8; ++j) {
    int n = j*16 + fr;
    #pragma unroll
    for (int r = 0; r < 4; ++r) {
      int p = wave*16 + fq*4 + r;
      cs[csb + p*128 + n] = f2us(accs[j][r]);
    }
  }
}

// ---- B: inter-chunk running-state scan ----
__global__ __launch_bounds__(256) void ssd_scan_states(
    unsigned short* __restrict__ cs, const float* __restrict__ acs) {
  int idx = blockIdx.x * 256 + threadIdx.x;
  int e  = idx & 8191;
  int bh = idx >> 13;
  float S = 0.f;
  for (int c = 0; c < NCHUNK; ++c) {
    float al = acs[((size_t)bh*NCHUNK + c)*64 + 63];
    size_t o = ((size_t)bh*NCHUNK + c)*(HEADDIM*DSTATE) + e;
    S = S * expf(al) + us2f(cs[o]);
    cs[o] = f2us(S);
  }
}

// ---- C (MFMA) ----
__global__ __launch_bounds__(256, 4) void ssd_phase_c_mfma(
    const unsigned short* __restrict__ bcact, const unsigned short* __restrict__ cs,
    const float* __restrict__ acs, unsigned short* __restrict__ yscan) {
  const int h = blockIdx.x & 63;
  const int c = (blockIdx.x >> 6) & 31;
  const int b = blockIdx.x >> 11;
  const int tid = threadIdx.x;
  const int t0 = b * SEQ + c * CHUNK;
  const int lane = tid & 63, wave = tid >> 6;
  const int fr = lane & 15, fq = lane >> 4;

  __shared__ __align__(16) unsigned short sC[64*136];
  __shared__ __align__(16) unsigned short sS[64*136];
  __shared__ float seAc[64];

  const size_t csb = ((size_t)((b*NHEADS + h)*NCHUNK + c)) * (HEADDIM*DSTATE);
  for (int i = tid; i < 8192; i += 256) {
    int p = i >> 7, n = i & 127;
    sS[p*136 + n] = cs[csb + i];
  }
  for (int i = tid; i < 8192; i += 256) {
    int l = i >> 7, n = i & 127;
    sC[l*136 + n] = bcact[(size_t)(t0 + l) * 256 + 128 + n];
  }
  if (tid < 64) seAc[tid] = expf(acs[((size_t)((b*NHEADS + h)*NCHUNK + c))*64 + tid]);
  __syncthreads();

  floatx4 acc[4];
  #pragma unroll
  for (int j = 0; j < 4; ++j) acc[j] = (floatx4){0.f, 0.f, 0.f, 0.f};
  #pragma unroll
  for (int k0 = 0; k0 < 128; k0 += 32) {
    short8 af = *(const short8*)(sC + (wave*16 + fr)*136 + k0 + fq*8);
    #pragma unroll
    for (int j = 0; j < 4; ++j) {
      short8 bf = *(const short8*)(sS + (j*16 + fr)*136 + k0 + fq*8);
      acc[j] = __builtin_amdgcn_mfma_f32_16x16x32_bf16(af, bf, acc[j], 0, 0, 0);
    }
  }
  #pragma unroll
  for (int j = 0; j < 4; ++j) {
    int p = j*16 + fr;
    #pragma unroll
    for (int r = 0; r < 4; ++r) {
      int l = wave*16 + fq*4 + r;
      size_t yi = (size_t)(t0 + l) * DINNER + h*HEADDIM + p;
      yscan[yi] = f2us(us2f(yscan[yi]) + acc[j][r] * seAc[l]);
    }
  }
}

__global__ __launch_bounds__(256) void gate_rmsnorm2(
    const unsigned short* __restrict__ proj, const float* __restrict__ norm_w,
    unsigned short* __restrict__ yscan) {
  const int t = blockIdx.x;
  const int tid = threadIdx.x;
  __shared__ float ybuf[DINNER];
  __shared__ float wpart[4];
  __shared__ float sinv;
  float ss = 0.f;
  for (int i = tid; i < DINNER; i += 256) {
    float zv = us2f(proj[(size_t)t * NPROJ + i]);
    float yv = us2f(yscan[(size_t)t * DINNER + i]) * (zv / (1.f + expf(-zv)));
    ybuf[i] = yv;
    ss += yv * yv;
  }
  #pragma unroll
  for (int off = 32; off > 0; off >>= 1) ss += __shfl_down(ss, off, 64);
  if ((tid & 63) == 0) wpart[tid >> 6] = ss;
  __syncthreads();
  if (tid == 0) {
    float tot = wpart[0] + wpart[1] + wpart[2] + wpart[3];
    sinv = 1.f / sqrtf(tot / (float)DINNER + 1e-5f);
  }
  __syncthreads();
  float inv = sinv;
  for (int i = tid; i < DINNER; i += 256)
    yscan[(size_t)t * DINNER + i] = f2us(ybuf[i] * inv * norm_w[i]);
}

// ================= FALLBACK path =================
__global__ __launch_bounds__(512) void ssd_fused(
    const unsigned short* __restrict__ proj, const float* __restrict__ dtr,
    const float* __restrict__ cw, const float* __restrict__ cb,
    const float* __restrict__ A_log, const float* __restrict__ dt_bias,
    unsigned short* __restrict__ yscan) {
  const int h = blockIdx.x & 63;
  const int b = blockIdx.x >> 6;
  const int tid = threadIdx.x;

  __shared__ unsigned short sB[64*130];
  __shared__ unsigned short sC[64*130];
  __shared__ unsigned short sX[64*66];
  __shared__ float sW[64*65];
  __shared__ float sdt[64], sAc[64], sdecay[64], seAc[64];

  const float Ah = -expf(A_log[h]);
  const float dbias = dt_bias[h];

  float S[16];
  #pragma unroll
  for (int j = 0; j < 16; ++j) S[j] = 0.f;

  const int lG  = tid >> 3;
  const int oc  = tid & 7;

  for (int c = 0; c < NCHUNK; ++c) {
    const int t0 = b * SEQ + c * CHUNK;
    __syncthreads();
    if (tid < 64) {
      float raw = dtr[(size_t)(t0 + tid) * NHEADS + h] + dbias;
      sdt[tid] = (raw > 20.f) ? raw : log1pf(expf(raw));
    }
    for (int i = tid; i < 64*256; i += 512) {
      int s = i >> 8, ch = i & 255;
      int cx = 4096 + ch;
      int lb = c * CHUNK + s;
      float acc = cb[cx];
      #pragma unroll
      for (int j = 0; j < 4; ++j) {
        int ll = lb - 3 + j;
        if (ll >= 0)
          acc += cw[cx*4 + j] * us2f(proj[(size_t)(b*SEQ + ll) * NPROJ + DINNER + cx]);
      }
      float v = acc / (1.f + expf(-acc));
      if (ch < 128) sB[s*130 + ch] = f2us(v);
      else          sC[s*130 + (ch - 128)] = f2us(v);
    }
    __syncthreads();
    if (tid == 0) {
      float run = 0.f;
      for (int s = 0; s < CHUNK; ++s) { run += sdt[s] * Ah; sAc[s] = run; }
    }
    __syncthreads();
    if (tid < 64) {
      float last = sAc[63];
      sdecay[tid] = expf(last - sAc[tid]);
      seAc[tid]   = expf(sAc[tid]);
    }
    for (int i = tid; i < 64*64; i += 512) {
      int s = i >> 6, p = i & 63;
      int cx = h * HEADDIM + p;
      int lb = c * CHUNK + s;
      float acc = cb[cx];
      #pragma unroll
      for (int j = 0; j < 4; ++j) {
        int ll = lb - 3 + j;
        if (ll >= 0)
          acc += cw[cx*4 + j] * us2f(proj[(size_t)(b*SEQ + ll) * NPROJ + DINNER + cx]);
      }
      float v = acc / (1.f + expf(-acc));
      sX[s*66 + p] = f2us(v * sdt[s]);
    }
    __syncthreads();

    float g[8];
    #pragma unroll
    for (int j = 0; j < 8; ++j) g[j] = 0.f;
    {
      const uint32_t* Cu = (const uint32_t*)&sC[lG * 130];
      for (int u = 0; u < 64; ++u) {
        uint32_t cv = Cu[u];
        float c0 = plo(cv), c1 = phi(cv);
        #pragma unroll
        for (int j = 0; j < 8; ++j) {
          uint32_t bv = ((const uint32_t*)&sB[(oc*8 + j) * 130])[u];
          g[j] += c0 * plo(bv) + c1 * phi(bv);
        }
      }
    }
    {
      float acl = sAc[lG];
      #pragma unroll
      for (int j = 0; j < 8; ++j) {
        int s = oc*8 + j;
        sW[lG*65 + s] = (s <= lG) ? g[j] * expf(acl - sAc[s]) : 0.f;
      }
    }
    {
      float elast = expf(sAc[63]);
      #pragma unroll
      for (int j = 0; j < 16; ++j) S[j] *= elast;
      for (int s = 0; s < CHUNK; ++s) {
        float w = sdecay[s] * us2f(sX[s*66 + lG]);
        const uint32_t* Bu = (const uint32_t*)&sB[s*130 + oc*16];
        #pragma unroll
        for (int ju = 0; ju < 8; ++ju) {
          uint32_t bv = Bu[ju];
          S[2*ju]   += plo(bv) * w;
          S[2*ju+1] += phi(bv) * w;
        }
      }
    }
    __syncthreads();
    #pragma unroll
    for (int j = 0; j < 16; ++j) sB[lG*130 + oc*16 + j] = f2us(S[j]);
    __syncthreads();
    for (int o = tid; o < CHUNK*HEADDIM; o += 512) {
      int l = o >> 6, p = o & 63;
      float yd = 0.f;
      for (int s = 0; s <= l; ++s)
        yd += sW[l*65 + s] * us2f(sX[s*66 + p]);
      float yo = 0.f;
      const uint32_t* Cu = (const uint32_t*)&sC[l * 130];
      const uint32_t* Su = (const uint32_t*)&sB[p * 130];
      for (int u = 0; u < 64; ++u) {
        uint32_t cv = Cu[u], sv = Su[u];
        yo += plo(cv) * plo(sv) + phi(cv) * phi(sv);
      }
      float y = yd + yo * seAc[l];
      yscan[(size_t)(t0 + l) * DINNER + h * HEADDIM + p] = f2us(y);
    }
  }
}

__global__ __launch_bounds__(256) void gate_rmsnorm_dskip(
    const unsigned short* __restrict__ proj, const float* __restrict__ cw,
    const float* __restrict__ cb, const float* __restrict__ Dv,
    const float* __restrict__ norm_w, unsigned short* __restrict__ yscan) {
  const int t = blockIdx.x;
  const int tid = threadIdx.x;
  const int b = t >> 11, lb = t & 2047;
  __shared__ float ybuf[DINNER];
  __shared__ float wpart[4];
  __shared__ float sinv;
  float ss = 0.f;
  for (int i = tid; i < DINNER; i += 256) {
    float zv = us2f(proj[(size_t)t * NPROJ + i]);
    float acc = cb[i];
    #pragma unroll
    for (int j = 0; j < 4; ++j) {
      int ll = lb - 3 + j;
      if (ll >= 0)
        acc += cw[i*4 + j] * us2f(proj[(size_t)(b*SEQ + ll) * NPROJ + DINNER + i]);
    }
    float xh = acc / (1.f + expf(-acc));
    float yv = us2f(yscan[(size_t)t * DINNER + i]) + xh * Dv[i >> 6];
    yv = yv * (zv / (1.f + expf(-zv)));
    ybuf[i] = yv;
    ss += yv * yv;
  }
  #pragma unroll
  for (int off = 32; off > 0; off >>= 1) ss += __shfl_down(ss, off, 64);
  if ((tid & 63) == 0) wpart[tid >> 6] = ss;
  __syncthreads();
  if (tid == 0) {
    float tot = wpart[0] + wpart[1] + wpart[2] + wpart[3];
    sinv = 1.f / sqrtf(tot / (float)DINNER + 1e-5f);
  }
  __syncthreads();
  float inv = sinv;
  for (int i = tid; i < DINNER; i += 256)
    yscan[(size_t)t * DINNER + i] = f2us(ybuf[i] * inv * norm_w[i]);
}

// ---------------- launch ----------------
extern "C" void kernel_launch(void* const* d_in, const int* in_sizes, int n_in,
                              void* d_out, int out_size, void* d_ws, size_t ws_size,
                              hipStream_t stream) {
  const float* x          = (const float*)d_in[0];
  const float* in_proj_w  = (const float*)d_in[1];
  const float* conv_w     = (const float*)d_in[2];
  const float* conv_b     = (const float*)d_in[3];
  const float* A_log      = (const float*)d_in[4];
  const float* Dv         = (const float*)d_in[5];
  const float* dt_bias    = (const float*)d_in[6];
  const float* norm_w     = (const float*)d_in[7];
  const float* out_proj_w = (const float*)d_in[8];
  float* out = (float*)d_out;

  unsigned short* proj  = (unsigned short*)d_ws;
  float*          dtr   = (float*)(proj + (size_t)TOKENS * NPROJ);
  unsigned short* yscan = (unsigned short*)(dtr + (size_t)TOKENS * NHEADS);
  unsigned short* cs    = yscan + (size_t)TOKENS * DINNER;
  float*          acs   = (float*)(cs + (size_t)B_SZ*NHEADS*NCHUNK*HEADDIM*DSTATE);
  unsigned short* bcact = (unsigned short*)(acs + (size_t)B_SZ*NHEADS*NCHUNK*64);
  float*          gbuf  = (float*)(bcact + (size_t)TOKENS*256);
  const size_t NEEDED = (size_t)((char*)(gbuf + (size_t)B_SZ*NCHUNK*4096) - (char*)d_ws);

  unsigned short* xb  = cs;                                  // TOKENS*DMODEL
  unsigned short* wib = xb + (size_t)TOKENS * DMODEL;        // NPROJ*DMODEL
  unsigned short* wob = proj;                                // DMODEL*DINNER

  if (ws_size >= NEEDED) {
    cast_f32_bf16<<<(TOKENS*DMODEL)/1024, 256, 0, stream>>>(x, xb, TOKENS*DMODEL);
    cast_f32_bf16<<<((size_t)NPROJ*DMODEL)/1024, 256, 0, stream>>>(in_proj_w, wib, NPROJ*DMODEL);
    {
      int nwg = (TOKENS/128) * (NPROJ/256);   // 32*33 = 1056, %8 == 0
      gemm_bt_p3<1><<<nwg, 256, 0, stream>>>(xb, wib, proj, TOKENS, NPROJ, DMODEL, TOKENS/128);
    }
    dt_gemm<<<TOKENS/64, 256, 0, stream>>>(x, in_proj_w, dtr);
    bc_conv_g<<<B_SZ*NCHUNK, 256, 0, stream>>>(proj, conv_w, conv_b, bcact, gbuf);
    ssd_phase_a2_mfma<<<B_SZ*NCHUNK*NHEADS, 256, 0, stream>>>(
        proj, bcact, dtr, conv_w, conv_b, A_log, dt_bias, gbuf, Dv, cs, acs, yscan);
    ssd_scan_states<<<(B_SZ*NHEADS*HEADDIM*DSTATE)/256, 256, 0, stream>>>(cs, acs);
    ssd_phase_c_mfma<<<B_SZ*NCHUNK*NHEADS, 256, 0, stream>>>(bcact, cs, acs, yscan);
    gate_rmsnorm2<<<TOKENS, 256, 0, stream>>>(proj, norm_w, yscan);
    cast_f32_bf16<<<((size_t)DMODEL*DINNER)/1024, 256, 0, stream>>>(out_proj_w, wob, DMODEL*DINNER);
    {
      int nwg = (TOKENS/128) * (DMODEL/256);  // 32*8 = 256, %8 == 0
      gemm_bt_p3<0><<<nwg, 256, 0, stream>>>(yscan, wob, out, TOKENS, DMODEL, DINNER, TOKENS/128);
    }
  } else {
    {
      dim3 grid(NPROJ/128, TOKENS/128);
      gemm_nt<float, unsigned short><<<grid, 256, 0, stream>>>(
          x, in_proj_w, proj, TOKENS, NPROJ, DMODEL);
    }
    dt_gemm<<<TOKENS/64, 256, 0, stream>>>(x, in_proj_w, dtr);
    ssd_fused<<<B_SZ*NHEADS, 512, 0, stream>>>(proj, dtr, conv_w, conv_b,
                                               A_log, dt_bias, yscan);
    gate_rmsnorm_dskip<<<TOKENS, 256, 0, stream>>>(proj, conv_w, conv_b, Dv, norm_w, yscan);
    {
      dim3 grid(DMODEL/128, TOKENS/128);
      gemm_nt<unsigned short, float><<<grid, 256, 0, stream>>>(
          yscan, out_proj_w, out, TOKENS, DMODEL, DINNER);
    }
  }
}